// Round 1
// 1131.689 us; speedup vs baseline: 1.0316x; 1.0316x over previous
//
#include <hip/hip_runtime.h>

// Problem constants: B=32, T=512, C=22, FREQ=192, HID=128
#define CC 22
#define FF 192
#define HH 128
#define NBT (32 * 512)

typedef __attribute__((ext_vector_type(8))) __bf16 bf16x8;
typedef __attribute__((ext_vector_type(4))) float f32x4;

__device__ __forceinline__ float bf2f(unsigned short u) {
    union { unsigned int i; float f; } v;
    v.i = ((unsigned int)u) << 16;
    return v.f;
}

// round-to-nearest-even f32 -> bf16
__device__ __forceinline__ unsigned short f2bf(float f) {
    union { float f; unsigned int i; } v;
    v.f = f;
    return (unsigned short)((v.i + 0x7fffu + ((v.i >> 16) & 1u)) >> 16);
}

// Probe: decide whether inputs are bf16 (flag=1) or fp32 (flag=0) by checking
// that A's first 64 ushorts, read as bf16, all lie in [0, 1.0001].
__global__ void detect_dtype(const unsigned short* __restrict__ A,
                             int* __restrict__ flag) {
    if (blockIdx.x == 0 && threadIdx.x == 0) {
        int ok = 1;
        for (int i = 0; i < 64; ++i) {
            float v = bf2f(A[i]);
            if (!(v >= 0.0f && v <= 1.0001f)) ok = 0;
        }
        *flag = ok;
    }
}

// ---------------------------------------------------------------------------
// fp32 fallback path (unchanged logic from the previous kernel)
// ---------------------------------------------------------------------------
__device__ void run_block_f32(
    const float* __restrict__ xg, const float* __restrict__ Ag,
    const float* __restrict__ W0g, const float* __restrict__ b0g,
    const float* __restrict__ W1g, const float* __restrict__ b1g,
    float* __restrict__ outg, int bt, int tid,
    float* sA, float* sX, float* sH1, float* sH2, float* sRed)
{
    const float* Ap = Ag + (size_t)bt * (CC * CC);
    for (int i = tid; i < CC * CC; i += 256) sA[i] = Ap[i];
    const float4* xp = (const float4*)(xg + (size_t)bt * (CC * FF));
    for (int i = tid; i < CC * FF / 4; i += 256) ((float4*)sX)[i] = xp[i];
    __syncthreads();

    for (int idx4 = tid; idx4 < CC * FF / 4; idx4 += 256) {
        const int c  = idx4 / (FF / 4);
        const int fq = idx4 - c * (FF / 4);
        float4 acc = make_float4(0.f, 0.f, 0.f, 0.f);
        #pragma unroll
        for (int j = 0; j < CC; ++j) {
            const float  a  = sA[c * CC + j];
            const float4 xv = *(const float4*)&sX[j * FF + 4 * fq];
            acc.x += a * xv.x; acc.y += a * xv.y;
            acc.z += a * xv.z; acc.w += a * xv.w;
        }
        ((float4*)sH1)[idx4] = acc;
    }
    __syncthreads();

    const int h  = tid & 127;
    const int ty = tid >> 7;

    {
        float acc[11];
        const float bb = b0g[h];
        #pragma unroll
        for (int i = 0; i < 11; ++i) acc[i] = bb;
        #pragma unroll 4
        for (int fq = 0; fq < FF / 4; ++fq) {
            float4 u = ((const float4*)(W0g + h * FF))[fq];
            #pragma unroll
            for (int i = 0; i < 11; ++i) {
                const float4 xv = *(const float4*)&sH1[(2 * i + ty) * FF + 4 * fq];
                acc[i] = fmaf(xv.x, u.x, fmaf(xv.y, u.y, fmaf(xv.z, u.z, fmaf(xv.w, u.w, acc[i]))));
            }
        }
        #pragma unroll
        for (int i = 0; i < 11; ++i)
            sH2[(2 * i + ty) * HH + h] = fmaxf(acc[i], 0.f);
    }
    __syncthreads();

    float* sH3 = sX;
    for (int idx4 = tid; idx4 < CC * HH / 4; idx4 += 256) {
        const int c  = idx4 / (HH / 4);
        const int kq = idx4 - c * (HH / 4);
        float4 acc = make_float4(0.f, 0.f, 0.f, 0.f);
        #pragma unroll
        for (int j = 0; j < CC; ++j) {
            const float  a  = sA[c * CC + j];
            const float4 xv = *(const float4*)&sH2[j * HH + 4 * kq];
            acc.x += a * xv.x; acc.y += a * xv.y;
            acc.z += a * xv.z; acc.w += a * xv.w;
        }
        ((float4*)sH3)[idx4] = acc;
    }
    __syncthreads();

    {
        float acc[11];
        const float bb = b1g[h];
        #pragma unroll
        for (int i = 0; i < 11; ++i) acc[i] = bb;
        #pragma unroll 4
        for (int kq = 0; kq < HH / 4; ++kq) {
            float4 u = ((const float4*)(W1g + h * HH))[kq];
            #pragma unroll
            for (int i = 0; i < 11; ++i) {
                const float4 xv = *(const float4*)&sH3[(2 * i + ty) * HH + 4 * kq];
                acc[i] = fmaf(xv.x, u.x, fmaf(xv.y, u.y, fmaf(xv.z, u.z, fmaf(xv.w, u.w, acc[i]))));
            }
        }
        float s = 0.f;
        #pragma unroll
        for (int i = 0; i < 11; ++i) s += fmaxf(acc[i], 0.f);
        sRed[ty * HH + h] = s;
    }
    __syncthreads();

    if (ty == 0) {
        const float m = (sRed[h] + sRed[HH + h]) * (1.0f / 22.0f);
        outg[(size_t)bt * HH + h] = m;
    }
}

// ---------------------------------------------------------------------------
// bf16 MFMA path.
//
// Layout chain (all MFMA 16x16x32_bf16, fp32 accum; D layout col=lane&15,
// row=(lane>>4)*4+r, so the TRANSPOSED store of each D is 4 contiguous bf16):
//   stage : xT[192][40] (j zero-padded to 32), Am[32][40] (rows/cols >=22 = 0)
//   P2    : D=xT.A^T -> store h1[c][f]        [32][200]
//   P3    : D=h1.W0^T+b0, relu, mask c>=22 -> store h2T[h][c]  [128][40]
//   P4    : D=h2T.A^T -> store h3[c][h]       [32][136]
//   P5    : D=W1.h3^T+b1, relu -> shfl-reduce over c, mean, store out bf16
// Strides 40/200/136 elems => 80/400/272-byte rows: 16B-aligned b128 frags,
// bank stride ≡ 4 or 20 (mod 32) => ≤2-way conflicts (free).
// ---------------------------------------------------------------------------
__device__ void run_block_bf16(
    const unsigned short* __restrict__ xg, const unsigned short* __restrict__ Ag,
    const unsigned short* __restrict__ W0g, const unsigned short* __restrict__ b0g,
    const unsigned short* __restrict__ W1g, const unsigned short* __restrict__ b1g,
    unsigned short* __restrict__ outg, int bt, int tid, char* smem)
{
    unsigned short* sXT  = (unsigned short*)smem;              // [192][40] 15360B
    unsigned short* sAm  = (unsigned short*)(smem + 15360);    // [32][40]   2560B
    unsigned short* sH1  = (unsigned short*)(smem + 17920);    // [32][200] 12800B
    unsigned short* sH2T = (unsigned short*)(smem + 30720);    // [128][40] 10240B
    unsigned short* sH3  = (unsigned short*)(smem + 40960);    // [32][136]  8704B

    const unsigned short* xp = xg + (size_t)bt * (CC * FF);
    const unsigned short* Ap = Ag + (size_t)bt * (CC * CC);

    // ---- stage A: [32][40], zero-padded everywhere outside [22][22] ----
    for (int id = tid; id < 32 * 40; id += 256) {
        const int r = id / 40;
        const int c = id - r * 40;
        sAm[id] = (r < CC && c < CC) ? Ap[r * CC + c] : (unsigned short)0;
    }
    // ---- zero xT pad cols j = 22..39 (as uint writes, cols 22..39 = 9 uints) ----
    for (int id = tid; id < FF * 9; id += 256) {
        const int f = id / 9;
        const int q = id - f * 9;
        ((unsigned int*)sXT)[f * 20 + 11 + q] = 0u;
    }
    // ---- transpose x -> sXT[f][j]; consecutive threads take consecutive j
    //      (coalesces LDS write banks; global reads are L1-absorbed) ----
    for (int id = tid; id < 24 * CC; id += 256) {   // 24 f-blocks x 22 rows
        const int fb = id / CC;
        const int j  = id - fb * CC;
        const uint4 v = *(const uint4*)(xp + j * FF + fb * 8);
        unsigned short* d = sXT + (fb * 8) * 40 + j;
        d[0 * 40] = (unsigned short)(v.x & 0xffffu);
        d[1 * 40] = (unsigned short)(v.x >> 16);
        d[2 * 40] = (unsigned short)(v.y & 0xffffu);
        d[3 * 40] = (unsigned short)(v.y >> 16);
        d[4 * 40] = (unsigned short)(v.z & 0xffffu);
        d[5 * 40] = (unsigned short)(v.z >> 16);
        d[6 * 40] = (unsigned short)(v.w & 0xffffu);
        d[7 * 40] = (unsigned short)(v.w >> 16);
    }
    __syncthreads();

    const int lane = tid & 63;
    const int wid  = tid >> 6;
    const int lr   = lane & 15;   // frag row/col within 16
    const int lk   = lane >> 4;   // k-group (8 elems each)

    const f32x4 vzero = {0.f, 0.f, 0.f, 0.f};

    // ---- P2: D[f][c] = sum_j xT[f][j]*A[c][j] = h1[c][f]; 12 f-tiles x 2 c-tiles
    {
        f32x4 acc[3][2];
        #pragma unroll
        for (int i = 0; i < 3; ++i)
            #pragma unroll
            for (int j = 0; j < 2; ++j) acc[i][j] = vzero;

        bf16x8 xa[3], ab[2];
        #pragma unroll
        for (int i = 0; i < 3; ++i)
            xa[i] = *(const bf16x8*)(sXT + ((3 * wid + i) * 16 + lr) * 40 + lk * 8);
        #pragma unroll
        for (int j = 0; j < 2; ++j)
            ab[j] = *(const bf16x8*)(sAm + (j * 16 + lr) * 40 + lk * 8);

        #pragma unroll
        for (int i = 0; i < 3; ++i)
            #pragma unroll
            for (int j = 0; j < 2; ++j)
                acc[i][j] = __builtin_amdgcn_mfma_f32_16x16x32_bf16(xa[i], ab[j], acc[i][j], 0, 0, 0);

        #pragma unroll
        for (int i = 0; i < 3; ++i) {
            const int fbase = (3 * wid + i) * 16 + lk * 4;
            #pragma unroll
            for (int j = 0; j < 2; ++j) {
                const int c = j * 16 + lr;
                ushort4 st;
                st.x = f2bf(acc[i][j][0]);
                st.y = f2bf(acc[i][j][1]);
                st.z = f2bf(acc[i][j][2]);
                st.w = f2bf(acc[i][j][3]);
                *(ushort4*)(sH1 + c * 200 + fbase) = st;
            }
        }
    }
    __syncthreads();

    // ---- P3: D[c][h] = h1 @ W0^T + b0, relu; store h2T[h][c], c>=22 -> 0
    {
        f32x4 acc[2][2];
        #pragma unroll
        for (int nt = 0; nt < 2; ++nt) {
            const int hcol = (2 * wid + nt) * 16 + lr;
            const float bv = bf2f(b0g[hcol]);
            f32x4 bvv = {bv, bv, bv, bv};
            acc[0][nt] = bvv;
            acc[1][nt] = bvv;
        }
        #pragma unroll
        for (int ks = 0; ks < 6; ++ks) {
            bf16x8 af[2], bfr[2];
            #pragma unroll
            for (int mt = 0; mt < 2; ++mt)
                af[mt] = *(const bf16x8*)(sH1 + (mt * 16 + lr) * 200 + ks * 32 + lk * 8);
            #pragma unroll
            for (int nt = 0; nt < 2; ++nt)
                bfr[nt] = *(const bf16x8*)(W0g + ((size_t)((2 * wid + nt) * 16 + lr)) * FF + ks * 32 + lk * 8);
            #pragma unroll
            for (int mt = 0; mt < 2; ++mt)
                #pragma unroll
                for (int nt = 0; nt < 2; ++nt)
                    acc[mt][nt] = __builtin_amdgcn_mfma_f32_16x16x32_bf16(af[mt], bfr[nt], acc[mt][nt], 0, 0, 0);
        }
        #pragma unroll
        for (int mt = 0; mt < 2; ++mt) {
            const int cbase = mt * 16 + lk * 4;
            #pragma unroll
            for (int nt = 0; nt < 2; ++nt) {
                const int hcol = (2 * wid + nt) * 16 + lr;
                ushort4 st;
                st.x = (cbase + 0 < CC) ? f2bf(fmaxf(acc[mt][nt][0], 0.f)) : (unsigned short)0;
                st.y = (cbase + 1 < CC) ? f2bf(fmaxf(acc[mt][nt][1], 0.f)) : (unsigned short)0;
                st.z = (cbase + 2 < CC) ? f2bf(fmaxf(acc[mt][nt][2], 0.f)) : (unsigned short)0;
                st.w = (cbase + 3 < CC) ? f2bf(fmaxf(acc[mt][nt][3], 0.f)) : (unsigned short)0;
                *(ushort4*)(sH2T + hcol * 40 + cbase) = st;
            }
        }
    }
    __syncthreads();

    // ---- P4: D[h][c] = sum_j h2T[h][j]*A[c][j]; store h3[c][h]
    {
        f32x4 acc[2][2];
        #pragma unroll
        for (int mt = 0; mt < 2; ++mt)
            #pragma unroll
            for (int ct = 0; ct < 2; ++ct) acc[mt][ct] = vzero;

        bf16x8 af[2], bb[2];
        #pragma unroll
        for (int mt = 0; mt < 2; ++mt)
            af[mt] = *(const bf16x8*)(sH2T + ((2 * wid + mt) * 16 + lr) * 40 + lk * 8);
        #pragma unroll
        for (int ct = 0; ct < 2; ++ct)
            bb[ct] = *(const bf16x8*)(sAm + (ct * 16 + lr) * 40 + lk * 8);

        #pragma unroll
        for (int mt = 0; mt < 2; ++mt)
            #pragma unroll
            for (int ct = 0; ct < 2; ++ct)
                acc[mt][ct] = __builtin_amdgcn_mfma_f32_16x16x32_bf16(af[mt], bb[ct], acc[mt][ct], 0, 0, 0);

        #pragma unroll
        for (int mt = 0; mt < 2; ++mt) {
            const int hbase = (2 * wid + mt) * 16 + lk * 4;
            #pragma unroll
            for (int ct = 0; ct < 2; ++ct) {
                const int c = ct * 16 + lr;
                ushort4 st;
                st.x = f2bf(acc[mt][ct][0]);
                st.y = f2bf(acc[mt][ct][1]);
                st.z = f2bf(acc[mt][ct][2]);
                st.w = f2bf(acc[mt][ct][3]);
                *(ushort4*)(sH3 + c * 136 + hbase) = st;
            }
        }
    }
    __syncthreads();

    // ---- P5: D[o][c] = W1 @ h3^T + b1, relu; mean over c<22 -> out[o]
    {
        f32x4 acc[2][2];
        #pragma unroll
        for (int mt = 0; mt < 2; ++mt) {
            const ushort4 bu = *(const ushort4*)(b1g + (2 * wid + mt) * 16 + lk * 4);
            f32x4 bvv = {bf2f(bu.x), bf2f(bu.y), bf2f(bu.z), bf2f(bu.w)};
            acc[mt][0] = bvv;
            acc[mt][1] = bvv;
        }
        #pragma unroll
        for (int ks = 0; ks < 4; ++ks) {
            bf16x8 af[2], bfr[2];
            #pragma unroll
            for (int mt = 0; mt < 2; ++mt)
                af[mt] = *(const bf16x8*)(W1g + ((size_t)((2 * wid + mt) * 16 + lr)) * HH + ks * 32 + lk * 8);
            #pragma unroll
            for (int ct = 0; ct < 2; ++ct)
                bfr[ct] = *(const bf16x8*)(sH3 + (ct * 16 + lr) * 136 + ks * 32 + lk * 8);
            #pragma unroll
            for (int mt = 0; mt < 2; ++mt)
                #pragma unroll
                for (int ct = 0; ct < 2; ++ct)
                    acc[mt][ct] = __builtin_amdgcn_mfma_f32_16x16x32_bf16(af[mt], bfr[ct], acc[mt][ct], 0, 0, 0);
        }

        // per-lane partial over its two c values (c=lr and c=16+lr if <22)
        float s[2][4];
        #pragma unroll
        for (int mt = 0; mt < 2; ++mt)
            #pragma unroll
            for (int r = 0; r < 4; ++r) {
                float v = fmaxf(acc[mt][0][r], 0.f);
                if (lr < CC - 16) v += fmaxf(acc[mt][1][r], 0.f);
                s[mt][r] = v;
            }
        // butterfly over the 16-lane lr-group (lane bits 0..3)
        #pragma unroll
        for (int m = 1; m < 16; m <<= 1)
            #pragma unroll
            for (int mt = 0; mt < 2; ++mt)
                #pragma unroll
                for (int r = 0; r < 4; ++r)
                    s[mt][r] += __shfl_xor(s[mt][r], m);

        if (lr == 0) {
            const float inv = 1.0f / 22.0f;
            #pragma unroll
            for (int mt = 0; mt < 2; ++mt) {
                ushort4 st;
                st.x = f2bf(s[mt][0] * inv);
                st.y = f2bf(s[mt][1] * inv);
                st.z = f2bf(s[mt][2] * inv);
                st.w = f2bf(s[mt][3] * inv);
                *(ushort4*)(outg + (size_t)bt * HH + (2 * wid + mt) * 16 + lk * 4) = st;
            }
        }
    }
}

__global__ __launch_bounds__(256) void tgcn_kernel(
    const void* __restrict__ x, const void* __restrict__ A,
    const void* __restrict__ W0, const void* __restrict__ b0,
    const void* __restrict__ W1, const void* __restrict__ b1,
    void* __restrict__ out, const int* __restrict__ flag)
{
    __shared__ __align__(16) char smem[50688];

    const int tid = threadIdx.x;
    const int bt  = blockIdx.x;
    const int isbf = *flag;   // block-uniform branch

    if (isbf) {
        run_block_bf16((const unsigned short*)x, (const unsigned short*)A,
                       (const unsigned short*)W0, (const unsigned short*)b0,
                       (const unsigned short*)W1, (const unsigned short*)b1,
                       (unsigned short*)out, bt, tid, smem);
    } else {
        float* sA   = (float*)smem;                 // 484   -> 1936B
        float* sX   = (float*)(smem + 1936);        // 4224  -> 16896B
        float* sH1  = (float*)(smem + 18832);       // 4224  -> 16896B
        float* sH2  = (float*)(smem + 35728);       // 2816  -> 11264B
        float* sRed = (float*)(smem + 46992);       // 256   -> 1024B
        run_block_f32((const float*)x, (const float*)A,
                      (const float*)W0, (const float*)b0,
                      (const float*)W1, (const float*)b1,
                      (float*)out, bt, tid, sA, sX, sH1, sH2, sRed);
    }
}

extern "C" void kernel_launch(void* const* d_in, const int* in_sizes, int n_in,
                              void* d_out, int out_size, void* d_ws, size_t ws_size,
                              hipStream_t stream) {
    int* flag = (int*)d_ws;
    detect_dtype<<<1, 64, 0, stream>>>((const unsigned short*)d_in[1], flag);
    tgcn_kernel<<<NBT, 256, 0, stream>>>(
        d_in[0], d_in[1], d_in[2], d_in[3], d_in[4], d_in[5], d_out, flag);
}

// Round 2
// 789.504 us; speedup vs baseline: 1.4788x; 1.4334x over previous
//
#include <hip/hip_runtime.h>

// Problem constants: B=32, T=512, C=22, FREQ=192, HID=128
#define CC 22
#define FF 192
#define HH 128
#define NBT (32 * 512)

typedef __attribute__((ext_vector_type(8))) __bf16 bf16x8;
typedef __attribute__((ext_vector_type(8))) short s16x8;
typedef __attribute__((ext_vector_type(4))) float f32x4;

__device__ __forceinline__ float bf2f(unsigned short u) {
    union { unsigned int i; float f; } v;
    v.i = ((unsigned int)u) << 16;
    return v.f;
}

// round-to-nearest-even f32 -> bf16
__device__ __forceinline__ unsigned short f2bf(float f) {
    union { float f; unsigned int i; } v;
    v.f = f;
    return (unsigned short)((v.i + 0x7fffu + ((v.i >> 16) & 1u)) >> 16);
}

// split fp32 into hi+lo bf16 (lo = rne(v - hi)); v == hi + lo + O(2^-18 v)
__device__ __forceinline__ void split2(float v, unsigned short& h, unsigned short& l) {
    h = f2bf(v);
    float r = v - bf2f(h);
    l = f2bf(r);
}

__device__ __forceinline__ bf16x8 bzero8() {
    s16x8 z = {0, 0, 0, 0, 0, 0, 0, 0};
    return __builtin_bit_cast(bf16x8, z);
}

// Probe: inputs bf16 (flag=1) or fp32 (flag=0). A is uniform[0,1]; if bf16,
// every ushort read as bf16 lies in [0,1.0001]. (Confirmed in practice: the
// harness feeds fp32 -> flag=0.)
__global__ void detect_dtype(const unsigned short* __restrict__ A,
                             int* __restrict__ flag) {
    if (blockIdx.x == 0 && threadIdx.x == 0) {
        int ok = 1;
        for (int i = 0; i < 64; ++i) {
            float v = bf2f(A[i]);
            if (!(v >= 0.0f && v <= 1.0001f)) ok = 0;
        }
        *flag = ok;
    }
}

// ws layout (ushort indices, base = d_ws + 256B):
//   W0h [0,24576) W0l [24576,49152) W1h [49152,65536) W1l [65536,81920)
#define WS0H 0
#define WS0L 24576
#define WS1H 49152
#define WS1L 65536

__global__ void convert_weights(const float* __restrict__ W0g,
                                const float* __restrict__ W1g,
                                unsigned short* __restrict__ wsW,
                                const int* __restrict__ flag) {
    if (*flag) return;  // bf16 inputs: W pointers are not fp32, skip
    const int i = blockIdx.x * 256 + threadIdx.x;
    if (i < HH * FF) {
        unsigned short h, l;
        split2(W0g[i], h, l);
        wsW[WS0H + i] = h;
        wsW[WS0L + i] = l;
    } else {
        const int j = i - HH * FF;
        if (j < HH * HH) {
            unsigned short h, l;
            split2(W1g[j], h, l);
            wsW[WS1H + j] = h;
            wsW[WS1L + j] = l;
        }
    }
}

// ---------------------------------------------------------------------------
// fp32 VALU fallback (used only if workspace is too small for split weights)
// ---------------------------------------------------------------------------
__device__ void run_block_f32(
    const float* __restrict__ xg, const float* __restrict__ Ag,
    const float* __restrict__ W0g, const float* __restrict__ b0g,
    const float* __restrict__ W1g, const float* __restrict__ b1g,
    float* __restrict__ outg, int bt, int tid,
    float* sA, float* sX, float* sH1, float* sH2, float* sRed)
{
    const float* Ap = Ag + (size_t)bt * (CC * CC);
    for (int i = tid; i < CC * CC; i += 256) sA[i] = Ap[i];
    const float4* xp = (const float4*)(xg + (size_t)bt * (CC * FF));
    for (int i = tid; i < CC * FF / 4; i += 256) ((float4*)sX)[i] = xp[i];
    __syncthreads();

    for (int idx4 = tid; idx4 < CC * FF / 4; idx4 += 256) {
        const int c  = idx4 / (FF / 4);
        const int fq = idx4 - c * (FF / 4);
        float4 acc = make_float4(0.f, 0.f, 0.f, 0.f);
        #pragma unroll
        for (int j = 0; j < CC; ++j) {
            const float  a  = sA[c * CC + j];
            const float4 xv = *(const float4*)&sX[j * FF + 4 * fq];
            acc.x += a * xv.x; acc.y += a * xv.y;
            acc.z += a * xv.z; acc.w += a * xv.w;
        }
        ((float4*)sH1)[idx4] = acc;
    }
    __syncthreads();

    const int h  = tid & 127;
    const int ty = tid >> 7;

    {
        float acc[11];
        const float bb = b0g[h];
        #pragma unroll
        for (int i = 0; i < 11; ++i) acc[i] = bb;
        #pragma unroll 4
        for (int fq = 0; fq < FF / 4; ++fq) {
            float4 u = ((const float4*)(W0g + h * FF))[fq];
            #pragma unroll
            for (int i = 0; i < 11; ++i) {
                const float4 xv = *(const float4*)&sH1[(2 * i + ty) * FF + 4 * fq];
                acc[i] = fmaf(xv.x, u.x, fmaf(xv.y, u.y, fmaf(xv.z, u.z, fmaf(xv.w, u.w, acc[i]))));
            }
        }
        #pragma unroll
        for (int i = 0; i < 11; ++i)
            sH2[(2 * i + ty) * HH + h] = fmaxf(acc[i], 0.f);
    }
    __syncthreads();

    float* sH3 = sX;
    for (int idx4 = tid; idx4 < CC * HH / 4; idx4 += 256) {
        const int c  = idx4 / (HH / 4);
        const int kq = idx4 - c * (HH / 4);
        float4 acc = make_float4(0.f, 0.f, 0.f, 0.f);
        #pragma unroll
        for (int j = 0; j < CC; ++j) {
            const float  a  = sA[c * CC + j];
            const float4 xv = *(const float4*)&sH2[j * HH + 4 * kq];
            acc.x += a * xv.x; acc.y += a * xv.y;
            acc.z += a * xv.z; acc.w += a * xv.w;
        }
        ((float4*)sH3)[idx4] = acc;
    }
    __syncthreads();

    {
        float acc[11];
        const float bb = b1g[h];
        #pragma unroll
        for (int i = 0; i < 11; ++i) acc[i] = bb;
        #pragma unroll 4
        for (int kq = 0; kq < HH / 4; ++kq) {
            float4 u = ((const float4*)(W1g + h * HH))[kq];
            #pragma unroll
            for (int i = 0; i < 11; ++i) {
                const float4 xv = *(const float4*)&sH3[(2 * i + ty) * HH + 4 * kq];
                acc[i] = fmaf(xv.x, u.x, fmaf(xv.y, u.y, fmaf(xv.z, u.z, fmaf(xv.w, u.w, acc[i]))));
            }
        }
        float s = 0.f;
        #pragma unroll
        for (int i = 0; i < 11; ++i) s += fmaxf(acc[i], 0.f);
        sRed[ty * HH + h] = s;
    }
    __syncthreads();

    if (ty == 0) {
        const float m = (sRed[h] + sRed[HH + h]) * (1.0f / 22.0f);
        outg[(size_t)bt * HH + h] = m;
    }
}

// ---------------------------------------------------------------------------
// fp32 inputs, split-precision (hi+lo bf16, 3 MFMA combos) path.
//
// Reassociated layer 1: relu(A@x@W0^T + b0) = relu(A@(x@W0^T) + b0), so x is
// consumed row-major (K=f contiguous) -> NO transpose staging. Chain (all
// 16x16x32 bf16 MFMA, fp32 accum; transposed D store = contiguous b64):
//   P1: D1[c][h]  = x·W0^T                 -> store yT[h][c]    [128][40]
//   P2: D2[c'][h] = A·y + b0, relu         -> store h2T[h][c']  [128][40]
//   P3: D3[c'][h] = A·h2                   -> store h3[c'][h]   [32][136] (scalar)
//   P4: D4[o][c'] = W1·h3^T + b1, relu     -> mask c'<22, shfl-reduce, mean, f32 out
// A-operand A-frags are loaded once and reused for P2+P3. W0/W1 hi/lo come
// pre-split from the workspace (global, L1/L2 resident).
// ---------------------------------------------------------------------------
__device__ void run_block_split(
    const float* __restrict__ xg, const float* __restrict__ Ag,
    const float* __restrict__ b0g, const float* __restrict__ b1g,
    const unsigned short* __restrict__ wsW,
    float* __restrict__ outg, int bt, int tid, char* smem)
{
    // LDS layout (bytes): xh 0 (8800), xl 8800 (8800), Ah 17600 (2560),
    // Al 20160 (2560), yTh 22720 (10240), yTl 32960 (10240),
    // h2Th 43200 (10240), h2Tl 53440 (10240). h3 aliases x: h3h 0, h3l 8704.
    unsigned short* sxh   = (unsigned short*)smem;              // [22][200]
    unsigned short* sxl   = (unsigned short*)(smem + 8800);
    unsigned short* sAh   = (unsigned short*)(smem + 17600);    // [32][40]
    unsigned short* sAl   = (unsigned short*)(smem + 20160);
    unsigned short* syTh  = (unsigned short*)(smem + 22720);    // [128][40]
    unsigned short* syTl  = (unsigned short*)(smem + 32960);
    unsigned short* sh2Th = (unsigned short*)(smem + 43200);    // [128][40]
    unsigned short* sh2Tl = (unsigned short*)(smem + 53440);
    unsigned short* sh3h  = (unsigned short*)smem;              // [32][136]
    unsigned short* sh3l  = (unsigned short*)(smem + 8704);

    const unsigned short* W0h = wsW + WS0H;
    const unsigned short* W0l = wsW + WS0L;
    const unsigned short* W1h = wsW + WS1H;
    const unsigned short* W1l = wsW + WS1L;

    // ---- stage x [22][192] fp32 -> hi/lo [22][200] ----
    {
        const float4* xp4 = (const float4*)(xg + (size_t)bt * (CC * FF));
        for (int idx = tid; idx < CC * (FF / 4); idx += 256) {
            const int c = idx / (FF / 4);
            const int q = idx - c * (FF / 4);
            const float4 v = xp4[idx];
            ushort4 h4, l4;
            split2(v.x, h4.x, l4.x);
            split2(v.y, h4.y, l4.y);
            split2(v.z, h4.z, l4.z);
            split2(v.w, h4.w, l4.w);
            *(ushort4*)&sxh[c * 200 + 4 * q] = h4;
            *(ushort4*)&sxl[c * 200 + 4 * q] = l4;
        }
        // A [22][22] fp32 -> hi/lo [32][40] zero-padded
        const float* Ap = Ag + (size_t)bt * (CC * CC);
        for (int idx = tid; idx < 32 * 40; idx += 256) {
            const int r = idx / 40;
            const int c = idx - r * 40;
            unsigned short h = 0, l = 0;
            if (r < CC && c < CC) split2(Ap[r * CC + c], h, l);
            sAh[idx] = h;
            sAl[idx] = l;
        }
    }
    __syncthreads();

    const int lane = tid & 63;
    const int wid  = tid >> 6;
    const int lr   = lane & 15;   // fragment row/col within 16
    const int lk   = lane >> 4;   // k-group (8 elems each)
    const int hb   = wid * 32;    // this wave's h-column block

    const f32x4 vzero = {0.f, 0.f, 0.f, 0.f};

    // ---- P1: D1[c][h] = x @ W0^T (3-combo split); store yT[h][c] ----
    {
        f32x4 acc[2][2];
        #pragma unroll
        for (int mt = 0; mt < 2; ++mt)
            #pragma unroll
            for (int nt = 0; nt < 2; ++nt) acc[mt][nt] = vzero;

        #pragma unroll
        for (int ks = 0; ks < 6; ++ks) {
            bf16x8 xfh[2], xfl[2];
            #pragma unroll
            for (int mt = 0; mt < 2; ++mt) {
                const int row = mt * 16 + lr;
                const int rr  = (row < CC) ? row : 0;   // clamp (zeroed below)
                const int off = rr * 200 + ks * 32 + lk * 8;
                bf16x8 fh = *(const bf16x8*)(sxh + off);
                bf16x8 fl = *(const bf16x8*)(sxl + off);
                if (row >= CC) { fh = bzero8(); fl = bzero8(); }
                xfh[mt] = fh; xfl[mt] = fl;
            }
            bf16x8 wfh[2], wfl[2];
            #pragma unroll
            for (int nt = 0; nt < 2; ++nt) {
                const int hcol = hb + nt * 16 + lr;
                const int off  = hcol * FF + ks * 32 + lk * 8;
                wfh[nt] = *(const bf16x8*)(W0h + off);
                wfl[nt] = *(const bf16x8*)(W0l + off);
            }
            #pragma unroll
            for (int mt = 0; mt < 2; ++mt)
                #pragma unroll
                for (int nt = 0; nt < 2; ++nt) {
                    acc[mt][nt] = __builtin_amdgcn_mfma_f32_16x16x32_bf16(xfh[mt], wfh[nt], acc[mt][nt], 0, 0, 0);
                    acc[mt][nt] = __builtin_amdgcn_mfma_f32_16x16x32_bf16(xfl[mt], wfh[nt], acc[mt][nt], 0, 0, 0);
                    acc[mt][nt] = __builtin_amdgcn_mfma_f32_16x16x32_bf16(xfh[mt], wfl[nt], acc[mt][nt], 0, 0, 0);
                }
        }
        #pragma unroll
        for (int mt = 0; mt < 2; ++mt)
            #pragma unroll
            for (int nt = 0; nt < 2; ++nt) {
                const int hcol = hb + nt * 16 + lr;
                ushort4 h4, l4;
                split2(acc[mt][nt][0], h4.x, l4.x);
                split2(acc[mt][nt][1], h4.y, l4.y);
                split2(acc[mt][nt][2], h4.z, l4.z);
                split2(acc[mt][nt][3], h4.w, l4.w);
                *(ushort4*)&syTh[hcol * 40 + mt * 16 + lk * 4] = h4;
                *(ushort4*)&syTl[hcol * 40 + mt * 16 + lk * 4] = l4;
            }
    }
    __syncthreads();

    // A-operand fragments of A (rows c', k=j) — reused by P2 and P3
    bf16x8 Afh[2], Afl[2];
    #pragma unroll
    for (int mt = 0; mt < 2; ++mt) {
        const int off = (mt * 16 + lr) * 40 + lk * 8;
        Afh[mt] = *(const bf16x8*)(sAh + off);
        Afl[mt] = *(const bf16x8*)(sAl + off);
    }

    // ---- P2: D2[c'][h] = A @ y + b0, relu; store h2T[h][c'] ----
    {
        f32x4 acc[2][2];
        #pragma unroll
        for (int nt = 0; nt < 2; ++nt) {
            const float b = b0g[hb + nt * 16 + lr];
            const f32x4 bv = {b, b, b, b};
            acc[0][nt] = bv;
            acc[1][nt] = bv;
        }
        bf16x8 yfh[2], yfl[2];
        #pragma unroll
        for (int nt = 0; nt < 2; ++nt) {
            const int off = (hb + nt * 16 + lr) * 40 + lk * 8;
            yfh[nt] = *(const bf16x8*)(syTh + off);
            yfl[nt] = *(const bf16x8*)(syTl + off);
        }
        #pragma unroll
        for (int mt = 0; mt < 2; ++mt)
            #pragma unroll
            for (int nt = 0; nt < 2; ++nt) {
                acc[mt][nt] = __builtin_amdgcn_mfma_f32_16x16x32_bf16(Afh[mt], yfh[nt], acc[mt][nt], 0, 0, 0);
                acc[mt][nt] = __builtin_amdgcn_mfma_f32_16x16x32_bf16(Afl[mt], yfh[nt], acc[mt][nt], 0, 0, 0);
                acc[mt][nt] = __builtin_amdgcn_mfma_f32_16x16x32_bf16(Afh[mt], yfl[nt], acc[mt][nt], 0, 0, 0);
            }
        #pragma unroll
        for (int mt = 0; mt < 2; ++mt)
            #pragma unroll
            for (int nt = 0; nt < 2; ++nt) {
                const int hcol = hb + nt * 16 + lr;
                ushort4 h4, l4;
                split2(fmaxf(acc[mt][nt][0], 0.f), h4.x, l4.x);
                split2(fmaxf(acc[mt][nt][1], 0.f), h4.y, l4.y);
                split2(fmaxf(acc[mt][nt][2], 0.f), h4.z, l4.z);
                split2(fmaxf(acc[mt][nt][3], 0.f), h4.w, l4.w);
                *(ushort4*)&sh2Th[hcol * 40 + mt * 16 + lk * 4] = h4;
                *(ushort4*)&sh2Tl[hcol * 40 + mt * 16 + lk * 4] = l4;
            }
    }
    __syncthreads();

    // ---- P3: D3[c'][h] = A @ h2; store h3[c'][h] (row-major, scalar) ----
    {
        f32x4 acc[2][2];
        #pragma unroll
        for (int mt = 0; mt < 2; ++mt)
            #pragma unroll
            for (int nt = 0; nt < 2; ++nt) acc[mt][nt] = vzero;

        bf16x8 gfh[2], gfl[2];
        #pragma unroll
        for (int nt = 0; nt < 2; ++nt) {
            const int off = (hb + nt * 16 + lr) * 40 + lk * 8;
            gfh[nt] = *(const bf16x8*)(sh2Th + off);
            gfl[nt] = *(const bf16x8*)(sh2Tl + off);
        }
        #pragma unroll
        for (int mt = 0; mt < 2; ++mt)
            #pragma unroll
            for (int nt = 0; nt < 2; ++nt) {
                acc[mt][nt] = __builtin_amdgcn_mfma_f32_16x16x32_bf16(Afh[mt], gfh[nt], acc[mt][nt], 0, 0, 0);
                acc[mt][nt] = __builtin_amdgcn_mfma_f32_16x16x32_bf16(Afl[mt], gfh[nt], acc[mt][nt], 0, 0, 0);
                acc[mt][nt] = __builtin_amdgcn_mfma_f32_16x16x32_bf16(Afh[mt], gfl[nt], acc[mt][nt], 0, 0, 0);
            }
        __syncthreads();   // x region (aliased by h3) fully dead; also h2T consumed
        #pragma unroll
        for (int mt = 0; mt < 2; ++mt)
            #pragma unroll
            for (int nt = 0; nt < 2; ++nt) {
                const int col = hb + nt * 16 + lr;
                #pragma unroll
                for (int r = 0; r < 4; ++r) {
                    const int row = mt * 16 + lk * 4 + r;
                    unsigned short h, l;
                    split2(acc[mt][nt][r], h, l);
                    sh3h[row * 136 + col] = h;
                    sh3l[row * 136 + col] = l;
                }
            }
    }
    __syncthreads();

    // ---- P4: D4[o][c'] = W1 @ h3^T + b1, relu; mean over c'<22 ----
    {
        f32x4 acc[2][2];
        #pragma unroll
        for (int mt = 0; mt < 2; ++mt) {
            const float4 bv = *(const float4*)(b1g + hb + mt * 16 + lk * 4);
            const f32x4 bb = {bv.x, bv.y, bv.z, bv.w};
            acc[mt][0] = bb;
            acc[mt][1] = bb;
        }
        #pragma unroll
        for (int ks = 0; ks < 4; ++ks) {
            bf16x8 wfh[2], wfl[2], hfh[2], hfl[2];
            #pragma unroll
            for (int mt = 0; mt < 2; ++mt) {
                const int o   = hb + mt * 16 + lr;
                const int off = o * HH + ks * 32 + lk * 8;
                wfh[mt] = *(const bf16x8*)(W1h + off);
                wfl[mt] = *(const bf16x8*)(W1l + off);
            }
            #pragma unroll
            for (int ct = 0; ct < 2; ++ct) {
                const int off = (ct * 16 + lr) * 136 + ks * 32 + lk * 8;
                hfh[ct] = *(const bf16x8*)(sh3h + off);
                hfl[ct] = *(const bf16x8*)(sh3l + off);
            }
            #pragma unroll
            for (int mt = 0; mt < 2; ++mt)
                #pragma unroll
                for (int ct = 0; ct < 2; ++ct) {
                    acc[mt][ct] = __builtin_amdgcn_mfma_f32_16x16x32_bf16(wfh[mt], hfh[ct], acc[mt][ct], 0, 0, 0);
                    acc[mt][ct] = __builtin_amdgcn_mfma_f32_16x16x32_bf16(wfl[mt], hfh[ct], acc[mt][ct], 0, 0, 0);
                    acc[mt][ct] = __builtin_amdgcn_mfma_f32_16x16x32_bf16(wfh[mt], hfl[ct], acc[mt][ct], 0, 0, 0);
                }
        }
        // relu + mask invalid c' + reduce over the 16-lane lr group
        float s[2][4];
        #pragma unroll
        for (int mt = 0; mt < 2; ++mt)
            #pragma unroll
            for (int r = 0; r < 4; ++r) {
                float v = fmaxf(acc[mt][0][r], 0.f);          // c' = lr (0..15)
                if (lr < CC - 16) v += fmaxf(acc[mt][1][r], 0.f); // c' = 16+lr
                s[mt][r] = v;
            }
        #pragma unroll
        for (int m = 1; m < 16; m <<= 1)
            #pragma unroll
            for (int mt = 0; mt < 2; ++mt)
                #pragma unroll
                for (int r = 0; r < 4; ++r)
                    s[mt][r] += __shfl_xor(s[mt][r], m);

        if (lr == 0) {
            const float inv = 1.0f / 22.0f;
            #pragma unroll
            for (int mt = 0; mt < 2; ++mt) {
                float4 o4;
                o4.x = s[mt][0] * inv;
                o4.y = s[mt][1] * inv;
                o4.z = s[mt][2] * inv;
                o4.w = s[mt][3] * inv;
                *(float4*)(outg + (size_t)bt * HH + hb + mt * 16 + lk * 4) = o4;
            }
        }
    }
}

// ---------------------------------------------------------------------------
// bf16-input MFMA path (kept for the flag==1 contingency; untested on HW)
// ---------------------------------------------------------------------------
__device__ void run_block_bf16(
    const unsigned short* __restrict__ xg, const unsigned short* __restrict__ Ag,
    const unsigned short* __restrict__ W0g, const unsigned short* __restrict__ b0g,
    const unsigned short* __restrict__ W1g, const unsigned short* __restrict__ b1g,
    unsigned short* __restrict__ outg, int bt, int tid, char* smem)
{
    unsigned short* sXT  = (unsigned short*)smem;              // [192][40]
    unsigned short* sAm  = (unsigned short*)(smem + 15360);    // [32][40]
    unsigned short* sH1  = (unsigned short*)(smem + 17920);    // [32][200]
    unsigned short* sH2T = (unsigned short*)(smem + 30720);    // [128][40]
    unsigned short* sH3  = (unsigned short*)(smem + 40960);    // [32][136]

    const unsigned short* xp = xg + (size_t)bt * (CC * FF);
    const unsigned short* Ap = Ag + (size_t)bt * (CC * CC);

    for (int id = tid; id < 32 * 40; id += 256) {
        const int r = id / 40;
        const int c = id - r * 40;
        sAm[id] = (r < CC && c < CC) ? Ap[r * CC + c] : (unsigned short)0;
    }
    for (int id = tid; id < FF * 9; id += 256) {
        const int f = id / 9;
        const int q = id - f * 9;
        ((unsigned int*)sXT)[f * 20 + 11 + q] = 0u;
    }
    for (int id = tid; id < 24 * CC; id += 256) {
        const int fb = id / CC;
        const int j  = id - fb * CC;
        const uint4 v = *(const uint4*)(xp + j * FF + fb * 8);
        unsigned short* d = sXT + (fb * 8) * 40 + j;
        d[0 * 40] = (unsigned short)(v.x & 0xffffu);
        d[1 * 40] = (unsigned short)(v.x >> 16);
        d[2 * 40] = (unsigned short)(v.y & 0xffffu);
        d[3 * 40] = (unsigned short)(v.y >> 16);
        d[4 * 40] = (unsigned short)(v.z & 0xffffu);
        d[5 * 40] = (unsigned short)(v.z >> 16);
        d[6 * 40] = (unsigned short)(v.w & 0xffffu);
        d[7 * 40] = (unsigned short)(v.w >> 16);
    }
    __syncthreads();

    const int lane = tid & 63;
    const int wid  = tid >> 6;
    const int lr   = lane & 15;
    const int lk   = lane >> 4;
    const f32x4 vzero = {0.f, 0.f, 0.f, 0.f};

    {
        f32x4 acc[3][2];
        #pragma unroll
        for (int i = 0; i < 3; ++i)
            #pragma unroll
            for (int j = 0; j < 2; ++j) acc[i][j] = vzero;
        bf16x8 xa[3], ab[2];
        #pragma unroll
        for (int i = 0; i < 3; ++i)
            xa[i] = *(const bf16x8*)(sXT + ((3 * wid + i) * 16 + lr) * 40 + lk * 8);
        #pragma unroll
        for (int j = 0; j < 2; ++j)
            ab[j] = *(const bf16x8*)(sAm + (j * 16 + lr) * 40 + lk * 8);
        #pragma unroll
        for (int i = 0; i < 3; ++i)
            #pragma unroll
            for (int j = 0; j < 2; ++j)
                acc[i][j] = __builtin_amdgcn_mfma_f32_16x16x32_bf16(xa[i], ab[j], acc[i][j], 0, 0, 0);
        #pragma unroll
        for (int i = 0; i < 3; ++i) {
            const int fbase = (3 * wid + i) * 16 + lk * 4;
            #pragma unroll
            for (int j = 0; j < 2; ++j) {
                const int c = j * 16 + lr;
                ushort4 st;
                st.x = f2bf(acc[i][j][0]);
                st.y = f2bf(acc[i][j][1]);
                st.z = f2bf(acc[i][j][2]);
                st.w = f2bf(acc[i][j][3]);
                *(ushort4*)(sH1 + c * 200 + fbase) = st;
            }
        }
    }
    __syncthreads();

    {
        f32x4 acc[2][2];
        #pragma unroll
        for (int nt = 0; nt < 2; ++nt) {
            const float bv = bf2f(b0g[(2 * wid + nt) * 16 + lr]);
            f32x4 bvv = {bv, bv, bv, bv};
            acc[0][nt] = bvv;
            acc[1][nt] = bvv;
        }
        #pragma unroll
        for (int ks = 0; ks < 6; ++ks) {
            bf16x8 af[2], bfr[2];
            #pragma unroll
            for (int mt = 0; mt < 2; ++mt)
                af[mt] = *(const bf16x8*)(sH1 + (mt * 16 + lr) * 200 + ks * 32 + lk * 8);
            #pragma unroll
            for (int nt = 0; nt < 2; ++nt)
                bfr[nt] = *(const bf16x8*)(W0g + ((size_t)((2 * wid + nt) * 16 + lr)) * FF + ks * 32 + lk * 8);
            #pragma unroll
            for (int mt = 0; mt < 2; ++mt)
                #pragma unroll
                for (int nt = 0; nt < 2; ++nt)
                    acc[mt][nt] = __builtin_amdgcn_mfma_f32_16x16x32_bf16(af[mt], bfr[nt], acc[mt][nt], 0, 0, 0);
        }
        #pragma unroll
        for (int mt = 0; mt < 2; ++mt) {
            const int cbase = mt * 16 + lk * 4;
            #pragma unroll
            for (int nt = 0; nt < 2; ++nt) {
                const int hcol = (2 * wid + nt) * 16 + lr;
                ushort4 st;
                st.x = (cbase + 0 < CC) ? f2bf(fmaxf(acc[mt][nt][0], 0.f)) : (unsigned short)0;
                st.y = (cbase + 1 < CC) ? f2bf(fmaxf(acc[mt][nt][1], 0.f)) : (unsigned short)0;
                st.z = (cbase + 2 < CC) ? f2bf(fmaxf(acc[mt][nt][2], 0.f)) : (unsigned short)0;
                st.w = (cbase + 3 < CC) ? f2bf(fmaxf(acc[mt][nt][3], 0.f)) : (unsigned short)0;
                *(ushort4*)(sH2T + hcol * 40 + cbase) = st;
            }
        }
    }
    __syncthreads();

    {
        f32x4 acc[2][2];
        #pragma unroll
        for (int mt = 0; mt < 2; ++mt)
            #pragma unroll
            for (int ct = 0; ct < 2; ++ct) acc[mt][ct] = vzero;
        bf16x8 af[2], bb[2];
        #pragma unroll
        for (int mt = 0; mt < 2; ++mt)
            af[mt] = *(const bf16x8*)(sH2T + ((2 * wid + mt) * 16 + lr) * 40 + lk * 8);
        #pragma unroll
        for (int ct = 0; ct < 2; ++ct)
            bb[ct] = *(const bf16x8*)(sAm + (ct * 16 + lr) * 40 + lk * 8);
        #pragma unroll
        for (int mt = 0; mt < 2; ++mt)
            #pragma unroll
            for (int ct = 0; ct < 2; ++ct)
                acc[mt][ct] = __builtin_amdgcn_mfma_f32_16x16x32_bf16(af[mt], bb[ct], acc[mt][ct], 0, 0, 0);
        #pragma unroll
        for (int mt = 0; mt < 2; ++mt) {
            const int hbase = (2 * wid + mt) * 16 + lk * 4;
            #pragma unroll
            for (int ct = 0; ct < 2; ++ct) {
                const int c = ct * 16 + lr;
                ushort4 st;
                st.x = f2bf(acc[mt][ct][0]);
                st.y = f2bf(acc[mt][ct][1]);
                st.z = f2bf(acc[mt][ct][2]);
                st.w = f2bf(acc[mt][ct][3]);
                *(ushort4*)(sH3 + c * 136 + hbase) = st;
            }
        }
    }
    __syncthreads();

    {
        f32x4 acc[2][2];
        #pragma unroll
        for (int mt = 0; mt < 2; ++mt) {
            const ushort4 bu = *(const ushort4*)(b1g + (2 * wid + mt) * 16 + lk * 4);
            f32x4 bvv = {bf2f(bu.x), bf2f(bu.y), bf2f(bu.z), bf2f(bu.w)};
            acc[mt][0] = bvv;
            acc[mt][1] = bvv;
        }
        #pragma unroll
        for (int ks = 0; ks < 4; ++ks) {
            bf16x8 af[2], bfr[2];
            #pragma unroll
            for (int mt = 0; mt < 2; ++mt)
                af[mt] = *(const bf16x8*)(W1g + ((size_t)((2 * wid + mt) * 16 + lr)) * HH + ks * 32 + lk * 8);
            #pragma unroll
            for (int ct = 0; ct < 2; ++ct)
                bfr[ct] = *(const bf16x8*)(sH3 + (ct * 16 + lr) * 136 + ks * 32 + lk * 8);
            #pragma unroll
            for (int mt = 0; mt < 2; ++mt)
                #pragma unroll
                for (int ct = 0; ct < 2; ++ct)
                    acc[mt][ct] = __builtin_amdgcn_mfma_f32_16x16x32_bf16(af[mt], bfr[ct], acc[mt][ct], 0, 0, 0);
        }
        float s[2][4];
        #pragma unroll
        for (int mt = 0; mt < 2; ++mt)
            #pragma unroll
            for (int r = 0; r < 4; ++r) {
                float v = fmaxf(acc[mt][0][r], 0.f);
                if (lr < CC - 16) v += fmaxf(acc[mt][1][r], 0.f);
                s[mt][r] = v;
            }
        #pragma unroll
        for (int m = 1; m < 16; m <<= 1)
            #pragma unroll
            for (int mt = 0; mt < 2; ++mt)
                #pragma unroll
                for (int r = 0; r < 4; ++r)
                    s[mt][r] += __shfl_xor(s[mt][r], m);
        if (lr == 0) {
            const float inv = 1.0f / 22.0f;
            #pragma unroll
            for (int mt = 0; mt < 2; ++mt) {
                ushort4 st;
                st.x = f2bf(s[mt][0] * inv);
                st.y = f2bf(s[mt][1] * inv);
                st.z = f2bf(s[mt][2] * inv);
                st.w = f2bf(s[mt][3] * inv);
                *(ushort4*)(outg + (size_t)bt * HH + (2 * wid + mt) * 16 + lk * 4) = st;
            }
        }
    }
}

__global__ __launch_bounds__(256) void tgcn_kernel(
    const void* __restrict__ x, const void* __restrict__ A,
    const void* __restrict__ W0, const void* __restrict__ b0,
    const void* __restrict__ W1, const void* __restrict__ b1,
    void* __restrict__ out, const int* __restrict__ flag,
    const unsigned short* __restrict__ wsW, int use_split)
{
    __shared__ __align__(16) char smem[63680];

    const int tid = threadIdx.x;
    const int bt  = blockIdx.x;
    const int isbf = *flag;   // block-uniform branch

    if (isbf) {
        run_block_bf16((const unsigned short*)x, (const unsigned short*)A,
                       (const unsigned short*)W0, (const unsigned short*)b0,
                       (const unsigned short*)W1, (const unsigned short*)b1,
                       (unsigned short*)out, bt, tid, smem);
    } else if (use_split) {
        run_block_split((const float*)x, (const float*)A,
                        (const float*)b0, (const float*)b1,
                        wsW, (float*)out, bt, tid, smem);
    } else {
        float* sA   = (float*)smem;
        float* sX   = (float*)(smem + 1936);
        float* sH1  = (float*)(smem + 18832);
        float* sH2  = (float*)(smem + 35728);
        float* sRed = (float*)(smem + 46992);
        run_block_f32((const float*)x, (const float*)A,
                      (const float*)W0, (const float*)b0,
                      (const float*)W1, (const float*)b1,
                      (float*)out, bt, tid, sA, sX, sH1, sH2, sRed);
    }
}

extern "C" void kernel_launch(void* const* d_in, const int* in_sizes, int n_in,
                              void* d_out, int out_size, void* d_ws, size_t ws_size,
                              hipStream_t stream) {
    int* flag = (int*)d_ws;
    unsigned short* wsW = (unsigned short*)((char*)d_ws + 256);
    const int use_split = (ws_size >= (size_t)(256 + 81920 * 2)) ? 1 : 0;

    detect_dtype<<<1, 64, 0, stream>>>((const unsigned short*)d_in[1], flag);
    if (use_split)
        convert_weights<<<160, 256, 0, stream>>>(
            (const float*)d_in[2], (const float*)d_in[4], wsW, flag);
    tgcn_kernel<<<NBT, 256, 0, stream>>>(
        d_in[0], d_in[1], d_in[2], d_in[3], d_in[4], d_in[5], d_out, flag,
        wsW, use_split);
}

// Round 3
// 705.825 us; speedup vs baseline: 1.6541x; 1.1186x over previous
//
#include <hip/hip_runtime.h>

// Problem constants: B=32, T=512, C=22, FREQ=192, HID=128
#define CC 22
#define FF 192
#define HH 128
#define NBT (32 * 512)

typedef __attribute__((ext_vector_type(8))) __bf16 bf16x8;
typedef __attribute__((ext_vector_type(8))) short s16x8;
typedef __attribute__((ext_vector_type(4))) float f32x4;

__device__ __forceinline__ float bf2f(unsigned short u) {
    union { unsigned int i; float f; } v;
    v.i = ((unsigned int)u) << 16;
    return v.f;
}

// round-to-nearest-even f32 -> bf16
__device__ __forceinline__ unsigned short f2bf(float f) {
    union { float f; unsigned int i; } v;
    v.f = f;
    return (unsigned short)((v.i + 0x7fffu + ((v.i >> 16) & 1u)) >> 16);
}

// split fp32 into hi+lo bf16 (lo = rne(v - hi)); v == hi + lo + O(2^-18 v)
__device__ __forceinline__ void split2(float v, unsigned short& h, unsigned short& l) {
    h = f2bf(v);
    float r = v - bf2f(h);
    l = f2bf(r);
}

__device__ __forceinline__ bf16x8 bzero8() {
    s16x8 z = {0, 0, 0, 0, 0, 0, 0, 0};
    return __builtin_bit_cast(bf16x8, z);
}

// Self-detect: inputs bf16 (1) or fp32 (0). A is uniform[0,1]; if bf16, every
// ushort read as bf16 lies in [0,1.0001]. Each of 64 lanes checks one ushort;
// wave-uniform verdict via __all (same answer in every wave/block).
__device__ __forceinline__ int inputs_are_bf16(const unsigned short* __restrict__ A,
                                               int tid) {
    const float v = bf2f(A[tid & 63]);
    return __all(v >= 0.0f && v <= 1.0001f);
}

// ws layout (ushort indices, base = d_ws):
//   W0h [0,24576) W0l [24576,49152) W1h [49152,65536) W1l [65536,81920)
#define WS0H 0
#define WS0L 24576
#define WS1H 49152
#define WS1L 65536

__global__ void convert_weights(const float* __restrict__ W0g,
                                const float* __restrict__ W1g,
                                const unsigned short* __restrict__ Aany,
                                unsigned short* __restrict__ wsW) {
    if (inputs_are_bf16(Aany, threadIdx.x)) return;  // bf16 inputs: skip
    const int i = blockIdx.x * 256 + threadIdx.x;
    if (i < HH * FF) {
        unsigned short h, l;
        split2(W0g[i], h, l);
        wsW[WS0H + i] = h;
        wsW[WS0L + i] = l;
    } else {
        const int j = i - HH * FF;
        if (j < HH * HH) {
            unsigned short h, l;
            split2(W1g[j], h, l);
            wsW[WS1H + j] = h;
            wsW[WS1L + j] = l;
        }
    }
}

// ---------------------------------------------------------------------------
// fp32 VALU fallback (only if workspace too small for split weights).
// LDS re-aliased to fit 43200B: sH2:=sX, sH3:=sH1, sRed:=sA.
// ---------------------------------------------------------------------------
__device__ void run_block_f32(
    const float* __restrict__ xg, const float* __restrict__ Ag,
    const float* __restrict__ W0g, const float* __restrict__ b0g,
    const float* __restrict__ W1g, const float* __restrict__ b1g,
    float* __restrict__ outg, int bt, int tid,
    float* sA, float* sX, float* sH1)
{
    float* sH2  = sX;   // x dead after phase 2 (barrier-protected)
    float* sH3  = sH1;  // h1 dead after phase 3
    float* sRed = sA;   // A dead after phase 4

    const float* Ap = Ag + (size_t)bt * (CC * CC);
    for (int i = tid; i < CC * CC; i += 256) sA[i] = Ap[i];
    const float4* xp = (const float4*)(xg + (size_t)bt * (CC * FF));
    for (int i = tid; i < CC * FF / 4; i += 256) ((float4*)sX)[i] = xp[i];
    __syncthreads();

    // phase 2: h1 = A @ x
    for (int idx4 = tid; idx4 < CC * FF / 4; idx4 += 256) {
        const int c  = idx4 / (FF / 4);
        const int fq = idx4 - c * (FF / 4);
        float4 acc = make_float4(0.f, 0.f, 0.f, 0.f);
        #pragma unroll
        for (int j = 0; j < CC; ++j) {
            const float  a  = sA[c * CC + j];
            const float4 xv = *(const float4*)&sX[j * FF + 4 * fq];
            acc.x += a * xv.x; acc.y += a * xv.y;
            acc.z += a * xv.z; acc.w += a * xv.w;
        }
        ((float4*)sH1)[idx4] = acc;
    }
    __syncthreads();

    const int h  = tid & 127;
    const int ty = tid >> 7;

    // phase 3: h2 = relu(h1 @ W0^T + b0)  (writes into old x region)
    {
        float acc[11];
        const float bb = b0g[h];
        #pragma unroll
        for (int i = 0; i < 11; ++i) acc[i] = bb;
        #pragma unroll 4
        for (int fq = 0; fq < FF / 4; ++fq) {
            float4 u = ((const float4*)(W0g + h * FF))[fq];
            #pragma unroll
            for (int i = 0; i < 11; ++i) {
                const float4 xv = *(const float4*)&sH1[(2 * i + ty) * FF + 4 * fq];
                acc[i] = fmaf(xv.x, u.x, fmaf(xv.y, u.y, fmaf(xv.z, u.z, fmaf(xv.w, u.w, acc[i]))));
            }
        }
        #pragma unroll
        for (int i = 0; i < 11; ++i)
            sH2[(2 * i + ty) * HH + h] = fmaxf(acc[i], 0.f);
    }
    __syncthreads();

    // phase 4: h3 = A @ h2  (writes into old h1 region)
    for (int idx4 = tid; idx4 < CC * HH / 4; idx4 += 256) {
        const int c  = idx4 / (HH / 4);
        const int kq = idx4 - c * (HH / 4);
        float4 acc = make_float4(0.f, 0.f, 0.f, 0.f);
        #pragma unroll
        for (int j = 0; j < CC; ++j) {
            const float  a  = sA[c * CC + j];
            const float4 xv = *(const float4*)&sH2[j * HH + 4 * kq];
            acc.x += a * xv.x; acc.y += a * xv.y;
            acc.z += a * xv.z; acc.w += a * xv.w;
        }
        ((float4*)sH3)[idx4] = acc;
    }
    __syncthreads();

    // phase 5: out = mean_c relu(h3 @ W1^T + b1)
    {
        float acc[11];
        const float bb = b1g[h];
        #pragma unroll
        for (int i = 0; i < 11; ++i) acc[i] = bb;
        #pragma unroll 4
        for (int kq = 0; kq < HH / 4; ++kq) {
            float4 u = ((const float4*)(W1g + h * HH))[kq];
            #pragma unroll
            for (int i = 0; i < 11; ++i) {
                const float4 xv = *(const float4*)&sH3[(2 * i + ty) * HH + 4 * kq];
                acc[i] = fmaf(xv.x, u.x, fmaf(xv.y, u.y, fmaf(xv.z, u.z, fmaf(xv.w, u.w, acc[i]))));
            }
        }
        float s = 0.f;
        #pragma unroll
        for (int i = 0; i < 11; ++i) s += fmaxf(acc[i], 0.f);
        sRed[ty * HH + h] = s;  // sA region; A dead (barrier above)
    }
    __syncthreads();

    if (ty == 0) {
        const float m = (sRed[h] + sRed[HH + h]) * (1.0f / 22.0f);
        outg[(size_t)bt * HH + h] = m;
    }
}

// ---------------------------------------------------------------------------
// fp32 inputs, split-precision (hi+lo bf16, 3 MFMA combos) path.
//
//   P1: D1[c][h]  = x·W0^T              -> store yT[h][c]    (sy slab)
//   P2: D2[c'][h] = A·y + b0, relu      -> store h2T[h][c']  (SAME sy slab)
//   P3: D3[h][c'] = h2T·A^T (swapped)   -> store h3[c'][h]   (x region, ushort4)
//   P4: D4[o][c'] = W1·h3^T + b1, relu  -> mask c'<22, shfl-reduce, mean, f32 out
//
// P1->P2->P3 are intra-wave (each wave produces/consumes its own 32-col slab):
// no barriers needed there. Barriers: stage->P1, P1->P3 (x-region reuse),
// P3->P4 (cross-wave h3). LDS 43200B -> 3 blocks/CU.
// ---------------------------------------------------------------------------
__device__ void run_block_split(
    const float* __restrict__ xg, const float* __restrict__ Ag,
    const float* __restrict__ b0g, const float* __restrict__ b1g,
    const unsigned short* __restrict__ wsW,
    float* __restrict__ outg, int bt, int tid, char* smem)
{
    unsigned short* sxh  = (unsigned short*)smem;              // [22][200] 8800B
    unsigned short* sxl  = (unsigned short*)(smem + 8800);     // [22][200] 8800B
    unsigned short* sAh  = (unsigned short*)(smem + 17600);    // [32][40]  2560B
    unsigned short* sAl  = (unsigned short*)(smem + 20160);    // [32][40]  2560B
    unsigned short* syh  = (unsigned short*)(smem + 22720);    // [128][40] 10240B (y, then h2)
    unsigned short* syl  = (unsigned short*)(smem + 32960);    // [128][40] 10240B
    unsigned short* sh3h = (unsigned short*)smem;              // [32][136] 8704B (aliases x)
    unsigned short* sh3l = (unsigned short*)(smem + 8704);     // [32][136] 8704B

    const unsigned short* W0h = wsW + WS0H;
    const unsigned short* W0l = wsW + WS0L;
    const unsigned short* W1h = wsW + WS1H;
    const unsigned short* W1l = wsW + WS1L;

    // ---- stage x [22][192] fp32 -> hi/lo [22][200]; A -> hi/lo [32][40] ----
    {
        const float4* xp4 = (const float4*)(xg + (size_t)bt * (CC * FF));
        for (int idx = tid; idx < CC * (FF / 4); idx += 256) {
            const int c = idx / (FF / 4);
            const int q = idx - c * (FF / 4);
            const float4 v = xp4[idx];
            ushort4 h4, l4;
            split2(v.x, h4.x, l4.x);
            split2(v.y, h4.y, l4.y);
            split2(v.z, h4.z, l4.z);
            split2(v.w, h4.w, l4.w);
            *(ushort4*)&sxh[c * 200 + 4 * q] = h4;
            *(ushort4*)&sxl[c * 200 + 4 * q] = l4;
        }
        const float* Ap = Ag + (size_t)bt * (CC * CC);
        for (int idx = tid; idx < 32 * 40; idx += 256) {
            const int r = idx / 40;
            const int c = idx - r * 40;
            unsigned short h = 0, l = 0;
            if (r < CC && c < CC) split2(Ap[r * CC + c], h, l);
            sAh[idx] = h;
            sAl[idx] = l;
        }
    }
    __syncthreads();

    const int lane = tid & 63;
    const int wid  = tid >> 6;
    const int lr   = lane & 15;   // fragment row/col within 16
    const int lk   = lane >> 4;   // k-group (8 elems each)
    const int hb   = wid * 32;    // this wave's h-column block

    const f32x4 vzero = {0.f, 0.f, 0.f, 0.f};

    // ---- P1: D1[c][h] = x @ W0^T (3-combo); store yT[h][c] in own slab ----
    {
        f32x4 acc[2][2];
        #pragma unroll
        for (int mt = 0; mt < 2; ++mt)
            #pragma unroll
            for (int nt = 0; nt < 2; ++nt) acc[mt][nt] = vzero;

        #pragma unroll
        for (int ks = 0; ks < 6; ++ks) {
            bf16x8 xfh[2], xfl[2];
            #pragma unroll
            for (int mt = 0; mt < 2; ++mt) {
                const int row = mt * 16 + lr;
                const int rr  = (row < CC) ? row : 0;   // clamp (zeroed below)
                const int off = rr * 200 + ks * 32 + lk * 8;
                bf16x8 fh = *(const bf16x8*)(sxh + off);
                bf16x8 fl = *(const bf16x8*)(sxl + off);
                if (row >= CC) { fh = bzero8(); fl = bzero8(); }
                xfh[mt] = fh; xfl[mt] = fl;
            }
            bf16x8 wfh[2], wfl[2];
            #pragma unroll
            for (int nt = 0; nt < 2; ++nt) {
                const int hcol = hb + nt * 16 + lr;
                const int off  = hcol * FF + ks * 32 + lk * 8;
                wfh[nt] = *(const bf16x8*)(W0h + off);
                wfl[nt] = *(const bf16x8*)(W0l + off);
            }
            #pragma unroll
            for (int mt = 0; mt < 2; ++mt)
                #pragma unroll
                for (int nt = 0; nt < 2; ++nt) {
                    acc[mt][nt] = __builtin_amdgcn_mfma_f32_16x16x32_bf16(xfh[mt], wfh[nt], acc[mt][nt], 0, 0, 0);
                    acc[mt][nt] = __builtin_amdgcn_mfma_f32_16x16x32_bf16(xfl[mt], wfh[nt], acc[mt][nt], 0, 0, 0);
                    acc[mt][nt] = __builtin_amdgcn_mfma_f32_16x16x32_bf16(xfh[mt], wfl[nt], acc[mt][nt], 0, 0, 0);
                }
        }
        #pragma unroll
        for (int mt = 0; mt < 2; ++mt)
            #pragma unroll
            for (int nt = 0; nt < 2; ++nt) {
                const int hcol = hb + nt * 16 + lr;
                ushort4 h4, l4;
                split2(acc[mt][nt][0], h4.x, l4.x);
                split2(acc[mt][nt][1], h4.y, l4.y);
                split2(acc[mt][nt][2], h4.z, l4.z);
                split2(acc[mt][nt][3], h4.w, l4.w);
                *(ushort4*)&syh[hcol * 40 + mt * 16 + lk * 4] = h4;
                *(ushort4*)&syl[hcol * 40 + mt * 16 + lk * 4] = l4;
            }
    }
    // Barrier: all waves finished reading x (its region becomes h3 in P3).
    __syncthreads();

    // A-operand fragments of A (rows c', k=c) — reused by P2 (A-op) and P3 (B-op)
    bf16x8 Afh[2], Afl[2];
    #pragma unroll
    for (int t = 0; t < 2; ++t) {
        const int off = (t * 16 + lr) * 40 + lk * 8;
        Afh[t] = *(const bf16x8*)(sAh + off);
        Afl[t] = *(const bf16x8*)(sAl + off);
    }

    // ---- P2: D2[c'][h] = A @ y + b0, relu; h2T into SAME slab (intra-wave) ----
    {
        f32x4 acc[2][2];
        #pragma unroll
        for (int nt = 0; nt < 2; ++nt) {
            const float b = b0g[hb + nt * 16 + lr];
            const f32x4 bv = {b, b, b, b};
            acc[0][nt] = bv;
            acc[1][nt] = bv;
        }
        bf16x8 yfh[2], yfl[2];
        #pragma unroll
        for (int nt = 0; nt < 2; ++nt) {
            const int off = (hb + nt * 16 + lr) * 40 + lk * 8;
            yfh[nt] = *(const bf16x8*)(syh + off);
            yfl[nt] = *(const bf16x8*)(syl + off);
        }
        asm volatile("" ::: "memory");  // keep y reads before h2 writes
        #pragma unroll
        for (int mt = 0; mt < 2; ++mt)
            #pragma unroll
            for (int nt = 0; nt < 2; ++nt) {
                acc[mt][nt] = __builtin_amdgcn_mfma_f32_16x16x32_bf16(Afh[mt], yfh[nt], acc[mt][nt], 0, 0, 0);
                acc[mt][nt] = __builtin_amdgcn_mfma_f32_16x16x32_bf16(Afl[mt], yfh[nt], acc[mt][nt], 0, 0, 0);
                acc[mt][nt] = __builtin_amdgcn_mfma_f32_16x16x32_bf16(Afh[mt], yfl[nt], acc[mt][nt], 0, 0, 0);
            }
        #pragma unroll
        for (int mt = 0; mt < 2; ++mt)
            #pragma unroll
            for (int nt = 0; nt < 2; ++nt) {
                const int hcol = hb + nt * 16 + lr;
                ushort4 h4, l4;
                split2(fmaxf(acc[mt][nt][0], 0.f), h4.x, l4.x);
                split2(fmaxf(acc[mt][nt][1], 0.f), h4.y, l4.y);
                split2(fmaxf(acc[mt][nt][2], 0.f), h4.z, l4.z);
                split2(fmaxf(acc[mt][nt][3], 0.f), h4.w, l4.w);
                *(ushort4*)&syh[hcol * 40 + mt * 16 + lk * 4] = h4;
                *(ushort4*)&syl[hcol * 40 + mt * 16 + lk * 4] = l4;
            }
    }

    // ---- P3 (swapped): D3[h][c'] = h2T @ A^T; store h3[c'][h] (ushort4) ----
    {
        f32x4 acc[2][2];
        #pragma unroll
        for (int mt = 0; mt < 2; ++mt)
            #pragma unroll
            for (int ct = 0; ct < 2; ++ct) acc[mt][ct] = vzero;

        bf16x8 gfh[2], gfl[2];   // h2T rows h (own slab), k=c contiguous
        #pragma unroll
        for (int mt = 0; mt < 2; ++mt) {
            const int off = (hb + mt * 16 + lr) * 40 + lk * 8;
            gfh[mt] = *(const bf16x8*)(syh + off);
            gfl[mt] = *(const bf16x8*)(syl + off);
        }
        #pragma unroll
        for (int mt = 0; mt < 2; ++mt)
            #pragma unroll
            for (int ct = 0; ct < 2; ++ct) {
                acc[mt][ct] = __builtin_amdgcn_mfma_f32_16x16x32_bf16(gfh[mt], Afh[ct], acc[mt][ct], 0, 0, 0);
                acc[mt][ct] = __builtin_amdgcn_mfma_f32_16x16x32_bf16(gfl[mt], Afh[ct], acc[mt][ct], 0, 0, 0);
                acc[mt][ct] = __builtin_amdgcn_mfma_f32_16x16x32_bf16(gfh[mt], Afl[ct], acc[mt][ct], 0, 0, 0);
            }
        // D rows = h = hb + mt*16 + lk*4 + r (4 consecutive), cols = c' = ct*16+lr
        // -> transposed store h3[c'][h] is one ushort4 per (mt,ct)
        #pragma unroll
        for (int mt = 0; mt < 2; ++mt)
            #pragma unroll
            for (int ct = 0; ct < 2; ++ct) {
                const int cp = ct * 16 + lr;
                ushort4 h4, l4;
                split2(acc[mt][ct][0], h4.x, l4.x);
                split2(acc[mt][ct][1], h4.y, l4.y);
                split2(acc[mt][ct][2], h4.z, l4.z);
                split2(acc[mt][ct][3], h4.w, l4.w);
                *(ushort4*)&sh3h[cp * 136 + hb + mt * 16 + lk * 4] = h4;
                *(ushort4*)&sh3l[cp * 136 + hb + mt * 16 + lk * 4] = l4;
            }
    }
    __syncthreads();   // h3 is read cross-wave in P4

    // ---- P4: D4[o][c'] = W1 @ h3^T + b1, relu; mean over c'<22 ----
    {
        f32x4 acc[2][2];
        #pragma unroll
        for (int mt = 0; mt < 2; ++mt) {
            const float4 bv = *(const float4*)(b1g + hb + mt * 16 + lk * 4);
            const f32x4 bb = {bv.x, bv.y, bv.z, bv.w};
            acc[mt][0] = bb;
            acc[mt][1] = bb;
        }
        #pragma unroll
        for (int ks = 0; ks < 4; ++ks) {
            bf16x8 wfh[2], wfl[2], hfh[2], hfl[2];
            #pragma unroll
            for (int mt = 0; mt < 2; ++mt) {
                const int o   = hb + mt * 16 + lr;
                const int off = o * HH + ks * 32 + lk * 8;
                wfh[mt] = *(const bf16x8*)(W1h + off);
                wfl[mt] = *(const bf16x8*)(W1l + off);
            }
            #pragma unroll
            for (int ct = 0; ct < 2; ++ct) {
                const int off = (ct * 16 + lr) * 136 + ks * 32 + lk * 8;
                hfh[ct] = *(const bf16x8*)(sh3h + off);
                hfl[ct] = *(const bf16x8*)(sh3l + off);
            }
            #pragma unroll
            for (int mt = 0; mt < 2; ++mt)
                #pragma unroll
                for (int ct = 0; ct < 2; ++ct) {
                    acc[mt][ct] = __builtin_amdgcn_mfma_f32_16x16x32_bf16(wfh[mt], hfh[ct], acc[mt][ct], 0, 0, 0);
                    acc[mt][ct] = __builtin_amdgcn_mfma_f32_16x16x32_bf16(wfl[mt], hfh[ct], acc[mt][ct], 0, 0, 0);
                    acc[mt][ct] = __builtin_amdgcn_mfma_f32_16x16x32_bf16(wfh[mt], hfl[ct], acc[mt][ct], 0, 0, 0);
                }
        }
        float s[2][4];
        #pragma unroll
        for (int mt = 0; mt < 2; ++mt)
            #pragma unroll
            for (int r = 0; r < 4; ++r) {
                float v = fmaxf(acc[mt][0][r], 0.f);              // c' = lr
                if (lr < CC - 16) v += fmaxf(acc[mt][1][r], 0.f); // c' = 16+lr
                s[mt][r] = v;
            }
        #pragma unroll
        for (int m = 1; m < 16; m <<= 1)
            #pragma unroll
            for (int mt = 0; mt < 2; ++mt)
                #pragma unroll
                for (int r = 0; r < 4; ++r)
                    s[mt][r] += __shfl_xor(s[mt][r], m);

        if (lr == 0) {
            const float inv = 1.0f / 22.0f;
            #pragma unroll
            for (int mt = 0; mt < 2; ++mt) {
                float4 o4;
                o4.x = s[mt][0] * inv;
                o4.y = s[mt][1] * inv;
                o4.z = s[mt][2] * inv;
                o4.w = s[mt][3] * inv;
                *(float4*)(outg + (size_t)bt * HH + hb + mt * 16 + lk * 4) = o4;
            }
        }
    }
}

// ---------------------------------------------------------------------------
// bf16-input MFMA path (flag==1 contingency). sH3 aliases sXT (dead after P1).
// ---------------------------------------------------------------------------
__device__ void run_block_bf16(
    const unsigned short* __restrict__ xg, const unsigned short* __restrict__ Ag,
    const unsigned short* __restrict__ W0g, const unsigned short* __restrict__ b0g,
    const unsigned short* __restrict__ W1g, const unsigned short* __restrict__ b1g,
    unsigned short* __restrict__ outg, int bt, int tid, char* smem)
{
    unsigned short* sXT  = (unsigned short*)smem;              // [192][40] 15360B
    unsigned short* sAm  = (unsigned short*)(smem + 15360);    // [32][40]   2560B
    unsigned short* sH1  = (unsigned short*)(smem + 17920);    // [32][200] 12800B
    unsigned short* sH2T = (unsigned short*)(smem + 30720);    // [128][40] 10240B
    unsigned short* sH3  = (unsigned short*)smem;              // [32][136] aliases sXT

    const unsigned short* xp = xg + (size_t)bt * (CC * FF);
    const unsigned short* Ap = Ag + (size_t)bt * (CC * CC);

    for (int id = tid; id < 32 * 40; id += 256) {
        const int r = id / 40;
        const int c = id - r * 40;
        sAm[id] = (r < CC && c < CC) ? Ap[r * CC + c] : (unsigned short)0;
    }
    for (int id = tid; id < FF * 9; id += 256) {
        const int f = id / 9;
        const int q = id - f * 9;
        ((unsigned int*)sXT)[f * 20 + 11 + q] = 0u;
    }
    for (int id = tid; id < 24 * CC; id += 256) {
        const int fb = id / CC;
        const int j  = id - fb * CC;
        const uint4 v = *(const uint4*)(xp + j * FF + fb * 8);
        unsigned short* d = sXT + (fb * 8) * 40 + j;
        d[0 * 40] = (unsigned short)(v.x & 0xffffu);
        d[1 * 40] = (unsigned short)(v.x >> 16);
        d[2 * 40] = (unsigned short)(v.y & 0xffffu);
        d[3 * 40] = (unsigned short)(v.y >> 16);
        d[4 * 40] = (unsigned short)(v.z & 0xffffu);
        d[5 * 40] = (unsigned short)(v.z >> 16);
        d[6 * 40] = (unsigned short)(v.w & 0xffffu);
        d[7 * 40] = (unsigned short)(v.w >> 16);
    }
    __syncthreads();

    const int lane = tid & 63;
    const int wid  = tid >> 6;
    const int lr   = lane & 15;
    const int lk   = lane >> 4;
    const f32x4 vzero = {0.f, 0.f, 0.f, 0.f};

    {
        f32x4 acc[3][2];
        #pragma unroll
        for (int i = 0; i < 3; ++i)
            #pragma unroll
            for (int j = 0; j < 2; ++j) acc[i][j] = vzero;
        bf16x8 xa[3], ab[2];
        #pragma unroll
        for (int i = 0; i < 3; ++i)
            xa[i] = *(const bf16x8*)(sXT + ((3 * wid + i) * 16 + lr) * 40 + lk * 8);
        #pragma unroll
        for (int j = 0; j < 2; ++j)
            ab[j] = *(const bf16x8*)(sAm + (j * 16 + lr) * 40 + lk * 8);
        #pragma unroll
        for (int i = 0; i < 3; ++i)
            #pragma unroll
            for (int j = 0; j < 2; ++j)
                acc[i][j] = __builtin_amdgcn_mfma_f32_16x16x32_bf16(xa[i], ab[j], acc[i][j], 0, 0, 0);
        #pragma unroll
        for (int i = 0; i < 3; ++i) {
            const int fbase = (3 * wid + i) * 16 + lk * 4;
            #pragma unroll
            for (int j = 0; j < 2; ++j) {
                const int c = j * 16 + lr;
                ushort4 st;
                st.x = f2bf(acc[i][j][0]);
                st.y = f2bf(acc[i][j][1]);
                st.z = f2bf(acc[i][j][2]);
                st.w = f2bf(acc[i][j][3]);
                *(ushort4*)(sH1 + c * 200 + fbase) = st;
            }
        }
    }
    __syncthreads();

    {
        f32x4 acc[2][2];
        #pragma unroll
        for (int nt = 0; nt < 2; ++nt) {
            const float bv = bf2f(b0g[(2 * wid + nt) * 16 + lr]);
            f32x4 bvv = {bv, bv, bv, bv};
            acc[0][nt] = bvv;
            acc[1][nt] = bvv;
        }
        #pragma unroll
        for (int ks = 0; ks < 6; ++ks) {
            bf16x8 af[2], bfr[2];
            #pragma unroll
            for (int mt = 0; mt < 2; ++mt)
                af[mt] = *(const bf16x8*)(sH1 + (mt * 16 + lr) * 200 + ks * 32 + lk * 8);
            #pragma unroll
            for (int nt = 0; nt < 2; ++nt)
                bfr[nt] = *(const bf16x8*)(W0g + ((size_t)((2 * wid + nt) * 16 + lr)) * FF + ks * 32 + lk * 8);
            #pragma unroll
            for (int mt = 0; mt < 2; ++mt)
                #pragma unroll
                for (int nt = 0; nt < 2; ++nt)
                    acc[mt][nt] = __builtin_amdgcn_mfma_f32_16x16x32_bf16(af[mt], bfr[nt], acc[mt][nt], 0, 0, 0);
        }
        #pragma unroll
        for (int mt = 0; mt < 2; ++mt) {
            const int cbase = mt * 16 + lk * 4;
            #pragma unroll
            for (int nt = 0; nt < 2; ++nt) {
                const int hcol = (2 * wid + nt) * 16 + lr;
                ushort4 st;
                st.x = (cbase + 0 < CC) ? f2bf(fmaxf(acc[mt][nt][0], 0.f)) : (unsigned short)0;
                st.y = (cbase + 1 < CC) ? f2bf(fmaxf(acc[mt][nt][1], 0.f)) : (unsigned short)0;
                st.z = (cbase + 2 < CC) ? f2bf(fmaxf(acc[mt][nt][2], 0.f)) : (unsigned short)0;
                st.w = (cbase + 3 < CC) ? f2bf(fmaxf(acc[mt][nt][3], 0.f)) : (unsigned short)0;
                *(ushort4*)(sH2T + hcol * 40 + cbase) = st;
            }
        }
    }
    __syncthreads();

    {
        f32x4 acc[2][2];
        #pragma unroll
        for (int mt = 0; mt < 2; ++mt)
            #pragma unroll
            for (int ct = 0; ct < 2; ++ct) acc[mt][ct] = vzero;
        bf16x8 af[2], bb[2];
        #pragma unroll
        for (int mt = 0; mt < 2; ++mt)
            af[mt] = *(const bf16x8*)(sH2T + ((2 * wid + mt) * 16 + lr) * 40 + lk * 8);
        #pragma unroll
        for (int ct = 0; ct < 2; ++ct)
            bb[ct] = *(const bf16x8*)(sAm + (ct * 16 + lr) * 40 + lk * 8);
        #pragma unroll
        for (int mt = 0; mt < 2; ++mt)
            #pragma unroll
            for (int ct = 0; ct < 2; ++ct)
                acc[mt][ct] = __builtin_amdgcn_mfma_f32_16x16x32_bf16(af[mt], bb[ct], acc[mt][ct], 0, 0, 0);
        #pragma unroll
        for (int mt = 0; mt < 2; ++mt) {
            const int hbase = (2 * wid + mt) * 16 + lk * 4;
            #pragma unroll
            for (int ct = 0; ct < 2; ++ct) {
                const int c = ct * 16 + lr;
                ushort4 st;
                st.x = f2bf(acc[mt][ct][0]);
                st.y = f2bf(acc[mt][ct][1]);
                st.z = f2bf(acc[mt][ct][2]);
                st.w = f2bf(acc[mt][ct][3]);
                *(ushort4*)(sH3 + c * 136 + hbase) = st;
            }
        }
    }
    __syncthreads();

    {
        f32x4 acc[2][2];
        #pragma unroll
        for (int mt = 0; mt < 2; ++mt) {
            const ushort4 bu = *(const ushort4*)(b1g + (2 * wid + mt) * 16 + lk * 4);
            f32x4 bvv = {bf2f(bu.x), bf2f(bu.y), bf2f(bu.z), bf2f(bu.w)};
            acc[mt][0] = bvv;
            acc[mt][1] = bvv;
        }
        #pragma unroll
        for (int ks = 0; ks < 4; ++ks) {
            bf16x8 af[2], bfr[2];
            #pragma unroll
            for (int mt = 0; mt < 2; ++mt)
                af[mt] = *(const bf16x8*)(W1g + ((size_t)((2 * wid + mt) * 16 + lr)) * HH + ks * 32 + lk * 8);
            #pragma unroll
            for (int ct = 0; ct < 2; ++ct)
                bfr[ct] = *(const bf16x8*)(sH3 + (ct * 16 + lr) * 136 + ks * 32 + lk * 8);
            #pragma unroll
            for (int mt = 0; mt < 2; ++mt)
                #pragma unroll
                for (int ct = 0; ct < 2; ++ct)
                    acc[mt][ct] = __builtin_amdgcn_mfma_f32_16x16x32_bf16(af[mt], bfr[ct], acc[mt][ct], 0, 0, 0);
        }
        float s[2][4];
        #pragma unroll
        for (int mt = 0; mt < 2; ++mt)
            #pragma unroll
            for (int r = 0; r < 4; ++r) {
                float v = fmaxf(acc[mt][0][r], 0.f);
                if (lr < CC - 16) v += fmaxf(acc[mt][1][r], 0.f);
                s[mt][r] = v;
            }
        #pragma unroll
        for (int m = 1; m < 16; m <<= 1)
            #pragma unroll
            for (int mt = 0; mt < 2; ++mt)
                #pragma unroll
                for (int r = 0; r < 4; ++r)
                    s[mt][r] += __shfl_xor(s[mt][r], m);
        if (lr == 0) {
            const float inv = 1.0f / 22.0f;
            #pragma unroll
            for (int mt = 0; mt < 2; ++mt) {
                ushort4 st;
                st.x = f2bf(s[mt][0] * inv);
                st.y = f2bf(s[mt][1] * inv);
                st.z = f2bf(s[mt][2] * inv);
                st.w = f2bf(s[mt][3] * inv);
                *(ushort4*)(outg + (size_t)bt * HH + (2 * wid + mt) * 16 + lk * 4) = st;
            }
        }
    }
}

__global__ __launch_bounds__(256) void tgcn_kernel(
    const void* __restrict__ x, const void* __restrict__ A,
    const void* __restrict__ W0, const void* __restrict__ b0,
    const void* __restrict__ W1, const void* __restrict__ b1,
    void* __restrict__ out, const unsigned short* __restrict__ wsW,
    int use_split)
{
    __shared__ __align__(16) char smem[43200];   // 3 blocks/CU

    const int tid = threadIdx.x;
    const int bt  = blockIdx.x;
    const int isbf = inputs_are_bf16((const unsigned short*)A, tid);

    if (isbf) {
        run_block_bf16((const unsigned short*)x, (const unsigned short*)A,
                       (const unsigned short*)W0, (const unsigned short*)b0,
                       (const unsigned short*)W1, (const unsigned short*)b1,
                       (unsigned short*)out, bt, tid, smem);
    } else if (use_split) {
        run_block_split((const float*)x, (const float*)A,
                        (const float*)b0, (const float*)b1,
                        wsW, (float*)out, bt, tid, smem);
    } else {
        float* sA  = (float*)smem;                 // 1936B (later sRed)
        float* sX  = (float*)(smem + 1936);        // 16896B (later h2)
        float* sH1 = (float*)(smem + 18832);       // 16896B (later h3)
        run_block_f32((const float*)x, (const float*)A,
                      (const float*)W0, (const float*)b0,
                      (const float*)W1, (const float*)b1,
                      (float*)out, bt, tid, sA, sX, sH1);
    }
}

extern "C" void kernel_launch(void* const* d_in, const int* in_sizes, int n_in,
                              void* d_out, int out_size, void* d_ws, size_t ws_size,
                              hipStream_t stream) {
    unsigned short* wsW = (unsigned short*)d_ws;
    const int use_split = (ws_size >= (size_t)(81920 * 2)) ? 1 : 0;

    if (use_split)
        convert_weights<<<160, 256, 0, stream>>>(
            (const float*)d_in[2], (const float*)d_in[4],
            (const unsigned short*)d_in[1], wsW);
    tgcn_kernel<<<NBT, 256, 0, stream>>>(
        d_in[0], d_in[1], d_in[2], d_in[3], d_in[4], d_in[5], d_out,
        wsW, use_split);
}

// Round 4
// 701.691 us; speedup vs baseline: 1.6638x; 1.0059x over previous
//
#include <hip/hip_runtime.h>

// Problem constants: B=32, T=512, C=22, FREQ=192, HID=128
#define CC 22
#define FF 192
#define HH 128
#define NBT (32 * 512)

typedef __attribute__((ext_vector_type(8))) __bf16 bf16x8;
typedef __attribute__((ext_vector_type(8))) short s16x8;
typedef __attribute__((ext_vector_type(4))) float f32x4;

__device__ __forceinline__ float bf2f(unsigned short u) {
    union { unsigned int i; float f; } v;
    v.i = ((unsigned int)u) << 16;
    return v.f;
}

// round-to-nearest-even f32 -> bf16 (scalar bit-trick; used on cold paths)
__device__ __forceinline__ unsigned short f2bf(float f) {
    union { float f; unsigned int i; } v;
    v.f = f;
    return (unsigned short)((v.i + 0x7fffu + ((v.i >> 16) & 1u)) >> 16);
}

__device__ __forceinline__ void split2(float v, unsigned short& h, unsigned short& l) {
    h = f2bf(v);
    float r = v - bf2f(h);
    l = f2bf(r);
}

// HW packed convert: dst.lo16 = bf16(a), dst.hi16 = bf16(b)  (RNE)
__device__ __forceinline__ unsigned int cvt_pk_bf16(float a, float b) {
    unsigned int r;
    asm("v_cvt_pk_bf16_f32 %0, %1, %2" : "=v"(r) : "v"(a), "v"(b));
    return r;
}

// split a PAIR of f32 into packed-hi and packed-lo bf16 dwords (6 VALU ops)
__device__ __forceinline__ void split_pk2(float a, float b,
                                          unsigned int& hi, unsigned int& lo) {
    hi = cvt_pk_bf16(a, b);
    union { unsigned int i; float f; } ha, hb;
    ha.i = hi << 16;
    hb.i = hi & 0xffff0000u;
    lo = cvt_pk_bf16(a - ha.f, b - hb.f);
}

__device__ __forceinline__ bf16x8 bzero8() {
    s16x8 z = {0, 0, 0, 0, 0, 0, 0, 0};
    return __builtin_bit_cast(bf16x8, z);
}

// y-slab addressing: [128][32] bf16 (64B rows), 2-bit XOR swizzle within row.
// b128 reads over 16 consecutive rows -> 2-way bank conflict (free).
__device__ __forceinline__ int ybyte(int row, int b) {
    return row * 64 + (b ^ (((row >> 1) & 3) << 4));
}

// Self-detect: inputs bf16 (1) or fp32 (0). A is uniform[0,1]; if bf16, every
// ushort read as bf16 lies in [0,1.0001]. Wave-uniform verdict via __all.
__device__ __forceinline__ int inputs_are_bf16(const unsigned short* __restrict__ A,
                                               int tid) {
    const float v = bf2f(A[tid & 63]);
    return __all(v >= 0.0f && v <= 1.0001f);
}

// ws layout (ushort indices, base = d_ws):
//   W0h [0,24576) W0l [24576,49152) W1h [49152,65536) W1l [65536,81920)
#define WS0H 0
#define WS0L 24576
#define WS1H 49152
#define WS1L 65536

__global__ void convert_weights(const float* __restrict__ W0g,
                                const float* __restrict__ W1g,
                                const unsigned short* __restrict__ Aany,
                                unsigned short* __restrict__ wsW) {
    if (inputs_are_bf16(Aany, threadIdx.x)) return;  // bf16 inputs: skip
    const int i = blockIdx.x * 256 + threadIdx.x;
    if (i < HH * FF) {
        unsigned short h, l;
        split2(W0g[i], h, l);
        wsW[WS0H + i] = h;
        wsW[WS0L + i] = l;
    } else {
        const int j = i - HH * FF;
        if (j < HH * HH) {
            unsigned short h, l;
            split2(W1g[j], h, l);
            wsW[WS1H + j] = h;
            wsW[WS1L + j] = l;
        }
    }
}

// ---------------------------------------------------------------------------
// fp32 VALU fallback (only if workspace too small for split weights).
// ---------------------------------------------------------------------------
__device__ void run_block_f32(
    const float* __restrict__ xg, const float* __restrict__ Ag,
    const float* __restrict__ W0g, const float* __restrict__ b0g,
    const float* __restrict__ W1g, const float* __restrict__ b1g,
    float* __restrict__ outg, int bt, int tid,
    float* sA, float* sX, float* sH1)
{
    float* sH2  = sX;   // x dead after phase 2 (barrier-protected)
    float* sH3  = sH1;  // h1 dead after phase 3
    float* sRed = sA;   // A dead after phase 4

    const float* Ap = Ag + (size_t)bt * (CC * CC);
    for (int i = tid; i < CC * CC; i += 256) sA[i] = Ap[i];
    const float4* xp = (const float4*)(xg + (size_t)bt * (CC * FF));
    for (int i = tid; i < CC * FF / 4; i += 256) ((float4*)sX)[i] = xp[i];
    __syncthreads();

    for (int idx4 = tid; idx4 < CC * FF / 4; idx4 += 256) {
        const int c  = idx4 / (FF / 4);
        const int fq = idx4 - c * (FF / 4);
        float4 acc = make_float4(0.f, 0.f, 0.f, 0.f);
        #pragma unroll
        for (int j = 0; j < CC; ++j) {
            const float  a  = sA[c * CC + j];
            const float4 xv = *(const float4*)&sX[j * FF + 4 * fq];
            acc.x += a * xv.x; acc.y += a * xv.y;
            acc.z += a * xv.z; acc.w += a * xv.w;
        }
        ((float4*)sH1)[idx4] = acc;
    }
    __syncthreads();

    const int h  = tid & 127;
    const int ty = tid >> 7;

    {
        float acc[11];
        const float bb = b0g[h];
        #pragma unroll
        for (int i = 0; i < 11; ++i) acc[i] = bb;
        #pragma unroll 4
        for (int fq = 0; fq < FF / 4; ++fq) {
            float4 u = ((const float4*)(W0g + h * FF))[fq];
            #pragma unroll
            for (int i = 0; i < 11; ++i) {
                const float4 xv = *(const float4*)&sH1[(2 * i + ty) * FF + 4 * fq];
                acc[i] = fmaf(xv.x, u.x, fmaf(xv.y, u.y, fmaf(xv.z, u.z, fmaf(xv.w, u.w, acc[i]))));
            }
        }
        #pragma unroll
        for (int i = 0; i < 11; ++i)
            sH2[(2 * i + ty) * HH + h] = fmaxf(acc[i], 0.f);
    }
    __syncthreads();

    for (int idx4 = tid; idx4 < CC * HH / 4; idx4 += 256) {
        const int c  = idx4 / (HH / 4);
        const int kq = idx4 - c * (HH / 4);
        float4 acc = make_float4(0.f, 0.f, 0.f, 0.f);
        #pragma unroll
        for (int j = 0; j < CC; ++j) {
            const float  a  = sA[c * CC + j];
            const float4 xv = *(const float4*)&sH2[j * HH + 4 * kq];
            acc.x += a * xv.x; acc.y += a * xv.y;
            acc.z += a * xv.z; acc.w += a * xv.w;
        }
        ((float4*)sH3)[idx4] = acc;
    }
    __syncthreads();

    {
        float acc[11];
        const float bb = b1g[h];
        #pragma unroll
        for (int i = 0; i < 11; ++i) acc[i] = bb;
        #pragma unroll 4
        for (int kq = 0; kq < HH / 4; ++kq) {
            float4 u = ((const float4*)(W1g + h * HH))[kq];
            #pragma unroll
            for (int i = 0; i < 11; ++i) {
                const float4 xv = *(const float4*)&sH3[(2 * i + ty) * HH + 4 * kq];
                acc[i] = fmaf(xv.x, u.x, fmaf(xv.y, u.y, fmaf(xv.z, u.z, fmaf(xv.w, u.w, acc[i]))));
            }
        }
        float s = 0.f;
        #pragma unroll
        for (int i = 0; i < 11; ++i) s += fmaxf(acc[i], 0.f);
        sRed[ty * HH + h] = s;
    }
    __syncthreads();

    if (ty == 0) {
        const float m = (sRed[h] + sRed[HH + h]) * (1.0f / 22.0f);
        outg[(size_t)bt * HH + h] = m;
    }
}

// ---------------------------------------------------------------------------
// fp32 inputs, split-precision (hi+lo bf16, 3 MFMA combos) path.
//
//   P1: D1[c][h]  = x·W0^T              -> store yT[h][c]    (swizzled y slab)
//   P2: D2[c'][h] = A·y + b0, relu      -> store h2T[h][c']  (SAME slab)
//   P3: D3[h][c'] = h2T·A^T (swapped)   -> store h3[c'][h]   (x region)
//   P4: D4[o][c'] = W1·h3^T + b1, relu  -> mask c'<22, shfl-reduce, mean, out
//
// P1->P2->P3 are intra-wave (own 32-col slab). Barriers: stage->P1,
// P1->P3 (x-region reuse), P3->P4 (cross-wave h3). LDS 39104B -> 4 blocks/CU.
// All f32->bf16 splits via packed v_cvt_pk_bf16_f32 (4x fewer VALU ops).
// ---------------------------------------------------------------------------
__device__ void run_block_split(
    const float* __restrict__ xg, const float* __restrict__ Ag,
    const float* __restrict__ b0g, const float* __restrict__ b1g,
    const unsigned short* __restrict__ wsW,
    float* __restrict__ outg, int bt, int tid, char* smem)
{
    unsigned short* sxh  = (unsigned short*)smem;              // [22][200] 8800B
    unsigned short* sxl  = (unsigned short*)(smem + 8800);     // [22][200] 8800B
    unsigned short* sAh  = (unsigned short*)(smem + 17600);    // [32][40]  2560B
    unsigned short* sAl  = (unsigned short*)(smem + 20160);    // [32][40]  2560B
    char*           syh  = smem + 22720;                        // [128][32] 8192B (y, then h2; swizzled)
    char*           syl  = smem + 30912;                        // [128][32] 8192B
    unsigned short* sh3h = (unsigned short*)smem;              // [32][136] 8704B (aliases x)
    unsigned short* sh3l = (unsigned short*)(smem + 8704);     // [32][136] 8704B

    const unsigned short* W0h = wsW + WS0H;
    const unsigned short* W0l = wsW + WS0L;
    const unsigned short* W1h = wsW + WS1H;
    const unsigned short* W1l = wsW + WS1L;

    // ---- stage x [22][192] fp32 -> hi/lo [22][200]; A -> hi/lo [32][40] ----
    {
        const float4* xp4 = (const float4*)(xg + (size_t)bt * (CC * FF));
        for (int idx = tid; idx < CC * (FF / 4); idx += 256) {
            const int c = idx / (FF / 4);
            const int q = idx - c * (FF / 4);
            const float4 v = xp4[idx];
            uint2 hv, lv;
            split_pk2(v.x, v.y, hv.x, lv.x);
            split_pk2(v.z, v.w, hv.y, lv.y);
            *(uint2*)&sxh[c * 200 + 4 * q] = hv;
            *(uint2*)&sxl[c * 200 + 4 * q] = lv;
        }
        const float* Ap = Ag + (size_t)bt * (CC * CC);
        for (int idx = tid; idx < 32 * 40; idx += 256) {
            const int r = idx / 40;
            const int c = idx - r * 40;
            unsigned short h = 0, l = 0;
            if (r < CC && c < CC) split2(Ap[r * CC + c], h, l);
            sAh[idx] = h;
            sAl[idx] = l;
        }
    }
    __syncthreads();

    const int lane = tid & 63;
    const int wid  = tid >> 6;
    const int lr   = lane & 15;   // fragment row/col within 16
    const int lk   = lane >> 4;   // k-group (8 elems each)
    const int hb   = wid * 32;    // this wave's h-column block

    const f32x4 vzero = {0.f, 0.f, 0.f, 0.f};

    // ---- P1: D1[c][h] = x @ W0^T (3-combo); store yT[h][c] in own slab ----
    {
        f32x4 acc[2][2];
        #pragma unroll
        for (int mt = 0; mt < 2; ++mt)
            #pragma unroll
            for (int nt = 0; nt < 2; ++nt) acc[mt][nt] = vzero;

        #pragma unroll
        for (int ks = 0; ks < 6; ++ks) {
            bf16x8 xfh[2], xfl[2];
            #pragma unroll
            for (int mt = 0; mt < 2; ++mt) {
                const int row = mt * 16 + lr;
                const int rr  = (row < CC) ? row : 0;   // clamp (zeroed below)
                const int off = rr * 200 + ks * 32 + lk * 8;
                bf16x8 fh = *(const bf16x8*)(sxh + off);
                bf16x8 fl = *(const bf16x8*)(sxl + off);
                if (row >= CC) { fh = bzero8(); fl = bzero8(); }
                xfh[mt] = fh; xfl[mt] = fl;
            }
            bf16x8 wfh[2], wfl[2];
            #pragma unroll
            for (int nt = 0; nt < 2; ++nt) {
                const int hcol = hb + nt * 16 + lr;
                const int off  = hcol * FF + ks * 32 + lk * 8;
                wfh[nt] = *(const bf16x8*)(W0h + off);
                wfl[nt] = *(const bf16x8*)(W0l + off);
            }
            #pragma unroll
            for (int mt = 0; mt < 2; ++mt)
                #pragma unroll
                for (int nt = 0; nt < 2; ++nt) {
                    acc[mt][nt] = __builtin_amdgcn_mfma_f32_16x16x32_bf16(xfh[mt], wfh[nt], acc[mt][nt], 0, 0, 0);
                    acc[mt][nt] = __builtin_amdgcn_mfma_f32_16x16x32_bf16(xfl[mt], wfh[nt], acc[mt][nt], 0, 0, 0);
                    acc[mt][nt] = __builtin_amdgcn_mfma_f32_16x16x32_bf16(xfh[mt], wfl[nt], acc[mt][nt], 0, 0, 0);
                }
        }
        #pragma unroll
        for (int mt = 0; mt < 2; ++mt)
            #pragma unroll
            for (int nt = 0; nt < 2; ++nt) {
                const int hcol = hb + nt * 16 + lr;
                uint2 hv, lv;
                split_pk2(acc[mt][nt][0], acc[mt][nt][1], hv.x, lv.x);
                split_pk2(acc[mt][nt][2], acc[mt][nt][3], hv.y, lv.y);
                const int boff = ybyte(hcol, mt * 32 + lk * 8);
                *(uint2*)(syh + boff) = hv;
                *(uint2*)(syl + boff) = lv;
            }
    }
    // Barrier: all waves finished reading x (its region becomes h3 in P3).
    __syncthreads();

    // A-operand fragments of A (rows c', k=c) — reused by P2 (A-op) and P3 (B-op)
    bf16x8 Afh[2], Afl[2];
    #pragma unroll
    for (int t = 0; t < 2; ++t) {
        const int off = (t * 16 + lr) * 40 + lk * 8;
        Afh[t] = *(const bf16x8*)(sAh + off);
        Afl[t] = *(const bf16x8*)(sAl + off);
    }

    // ---- P2: D2[c'][h] = A @ y + b0, relu; h2T into SAME slab (intra-wave) ----
    {
        f32x4 acc[2][2];
        #pragma unroll
        for (int nt = 0; nt < 2; ++nt) {
            const float b = b0g[hb + nt * 16 + lr];
            const f32x4 bv = {b, b, b, b};
            acc[0][nt] = bv;
            acc[1][nt] = bv;
        }
        bf16x8 yfh[2], yfl[2];
        #pragma unroll
        for (int nt = 0; nt < 2; ++nt) {
            const int boff = ybyte(hb + nt * 16 + lr, lk * 16);
            yfh[nt] = *(const bf16x8*)(syh + boff);
            yfl[nt] = *(const bf16x8*)(syl + boff);
        }
        asm volatile("" ::: "memory");  // keep y reads before h2 writes
        #pragma unroll
        for (int mt = 0; mt < 2; ++mt)
            #pragma unroll
            for (int nt = 0; nt < 2; ++nt) {
                acc[mt][nt] = __builtin_amdgcn_mfma_f32_16x16x32_bf16(Afh[mt], yfh[nt], acc[mt][nt], 0, 0, 0);
                acc[mt][nt] = __builtin_amdgcn_mfma_f32_16x16x32_bf16(Afl[mt], yfh[nt], acc[mt][nt], 0, 0, 0);
                acc[mt][nt] = __builtin_amdgcn_mfma_f32_16x16x32_bf16(Afh[mt], yfl[nt], acc[mt][nt], 0, 0, 0);
            }
        #pragma unroll
        for (int mt = 0; mt < 2; ++mt)
            #pragma unroll
            for (int nt = 0; nt < 2; ++nt) {
                const int hcol = hb + nt * 16 + lr;
                uint2 hv, lv;
                split_pk2(fmaxf(acc[mt][nt][0], 0.f), fmaxf(acc[mt][nt][1], 0.f), hv.x, lv.x);
                split_pk2(fmaxf(acc[mt][nt][2], 0.f), fmaxf(acc[mt][nt][3], 0.f), hv.y, lv.y);
                const int boff = ybyte(hcol, mt * 32 + lk * 8);
                *(uint2*)(syh + boff) = hv;
                *(uint2*)(syl + boff) = lv;
            }
    }

    // ---- P3 (swapped): D3[h][c'] = h2T @ A^T; store h3[c'][h] ----
    {
        f32x4 acc[2][2];
        #pragma unroll
        for (int mt = 0; mt < 2; ++mt)
            #pragma unroll
            for (int ct = 0; ct < 2; ++ct) acc[mt][ct] = vzero;

        bf16x8 gfh[2], gfl[2];   // h2T rows h (own slab), k=c contiguous
        #pragma unroll
        for (int mt = 0; mt < 2; ++mt) {
            const int boff = ybyte(hb + mt * 16 + lr, lk * 16);
            gfh[mt] = *(const bf16x8*)(syh + boff);
            gfl[mt] = *(const bf16x8*)(syl + boff);
        }
        #pragma unroll
        for (int mt = 0; mt < 2; ++mt)
            #pragma unroll
            for (int ct = 0; ct < 2; ++ct) {
                acc[mt][ct] = __builtin_amdgcn_mfma_f32_16x16x32_bf16(gfh[mt], Afh[ct], acc[mt][ct], 0, 0, 0);
                acc[mt][ct] = __builtin_amdgcn_mfma_f32_16x16x32_bf16(gfl[mt], Afh[ct], acc[mt][ct], 0, 0, 0);
                acc[mt][ct] = __builtin_amdgcn_mfma_f32_16x16x32_bf16(gfh[mt], Afl[ct], acc[mt][ct], 0, 0, 0);
            }
        // D rows = h = hb + mt*16 + lk*4 + r, cols = c' = ct*16 + lr
        // -> transposed store h3[c'][h]: one 8B hi + one 8B lo per (mt,ct)
        #pragma unroll
        for (int mt = 0; mt < 2; ++mt)
            #pragma unroll
            for (int ct = 0; ct < 2; ++ct) {
                const int cp = ct * 16 + lr;
                uint2 hv, lv;
                split_pk2(acc[mt][ct][0], acc[mt][ct][1], hv.x, lv.x);
                split_pk2(acc[mt][ct][2], acc[mt][ct][3], hv.y, lv.y);
                const int e = cp * 136 + hb + mt * 16 + lk * 4;
                *(uint2*)&sh3h[e] = hv;
                *(uint2*)&sh3l[e] = lv;
            }
    }
    __syncthreads();   // h3 is read cross-wave in P4

    // ---- P4: D4[o][c'] = W1 @ h3^T + b1, relu; mean over c'<22 ----
    {
        f32x4 acc[2][2];
        #pragma unroll
        for (int mt = 0; mt < 2; ++mt) {
            const float4 bv = *(const float4*)(b1g + hb + mt * 16 + lk * 4);
            const f32x4 bb = {bv.x, bv.y, bv.z, bv.w};
            acc[mt][0] = bb;
            acc[mt][1] = bb;
        }
        #pragma unroll
        for (int ks = 0; ks < 4; ++ks) {
            bf16x8 wfh[2], wfl[2], hfh[2], hfl[2];
            #pragma unroll
            for (int mt = 0; mt < 2; ++mt) {
                const int o   = hb + mt * 16 + lr;
                const int off = o * HH + ks * 32 + lk * 8;
                wfh[mt] = *(const bf16x8*)(W1h + off);
                wfl[mt] = *(const bf16x8*)(W1l + off);
            }
            #pragma unroll
            for (int ct = 0; ct < 2; ++ct) {
                const int off = (ct * 16 + lr) * 136 + ks * 32 + lk * 8;
                hfh[ct] = *(const bf16x8*)(sh3h + off);
                hfl[ct] = *(const bf16x8*)(sh3l + off);
            }
            #pragma unroll
            for (int mt = 0; mt < 2; ++mt)
                #pragma unroll
                for (int ct = 0; ct < 2; ++ct) {
                    acc[mt][ct] = __builtin_amdgcn_mfma_f32_16x16x32_bf16(wfh[mt], hfh[ct], acc[mt][ct], 0, 0, 0);
                    acc[mt][ct] = __builtin_amdgcn_mfma_f32_16x16x32_bf16(wfl[mt], hfh[ct], acc[mt][ct], 0, 0, 0);
                    acc[mt][ct] = __builtin_amdgcn_mfma_f32_16x16x32_bf16(wfh[mt], hfl[ct], acc[mt][ct], 0, 0, 0);
                }
        }
        float s[2][4];
        #pragma unroll
        for (int mt = 0; mt < 2; ++mt)
            #pragma unroll
            for (int r = 0; r < 4; ++r) {
                float v = fmaxf(acc[mt][0][r], 0.f);              // c' = lr
                if (lr < CC - 16) v += fmaxf(acc[mt][1][r], 0.f); // c' = 16+lr
                s[mt][r] = v;
            }
        #pragma unroll
        for (int m = 1; m < 16; m <<= 1)
            #pragma unroll
            for (int mt = 0; mt < 2; ++mt)
                #pragma unroll
                for (int r = 0; r < 4; ++r)
                    s[mt][r] += __shfl_xor(s[mt][r], m);

        if (lr == 0) {
            const float inv = 1.0f / 22.0f;
            #pragma unroll
            for (int mt = 0; mt < 2; ++mt) {
                float4 o4;
                o4.x = s[mt][0] * inv;
                o4.y = s[mt][1] * inv;
                o4.z = s[mt][2] * inv;
                o4.w = s[mt][3] * inv;
                *(float4*)(outg + (size_t)bt * HH + hb + mt * 16 + lk * 4) = o4;
            }
        }
    }
}

// ---------------------------------------------------------------------------
// bf16-input MFMA path (flag==1 contingency).
// LDS: sXT 0..15360, sAm 15360..17920, sH1 17920..30720;
//      sH2T aliases sXT (dead after P1), sH3 aliases sH1 (dead after P2 read).
// ---------------------------------------------------------------------------
__device__ void run_block_bf16(
    const unsigned short* __restrict__ xg, const unsigned short* __restrict__ Ag,
    const unsigned short* __restrict__ W0g, const unsigned short* __restrict__ b0g,
    const unsigned short* __restrict__ W1g, const unsigned short* __restrict__ b1g,
    unsigned short* __restrict__ outg, int bt, int tid, char* smem)
{
    unsigned short* sXT  = (unsigned short*)smem;              // [192][40] 15360B
    unsigned short* sAm  = (unsigned short*)(smem + 15360);    // [32][40]   2560B
    unsigned short* sH1  = (unsigned short*)(smem + 17920);    // [32][200] 12800B
    unsigned short* sH2T = (unsigned short*)smem;              // [128][40] aliases sXT
    unsigned short* sH3  = (unsigned short*)(smem + 17920);    // [32][136] aliases sH1

    const unsigned short* xp = xg + (size_t)bt * (CC * FF);
    const unsigned short* Ap = Ag + (size_t)bt * (CC * CC);

    for (int id = tid; id < 32 * 40; id += 256) {
        const int r = id / 40;
        const int c = id - r * 40;
        sAm[id] = (r < CC && c < CC) ? Ap[r * CC + c] : (unsigned short)0;
    }
    for (int id = tid; id < FF * 9; id += 256) {
        const int f = id / 9;
        const int q = id - f * 9;
        ((unsigned int*)sXT)[f * 20 + 11 + q] = 0u;
    }
    for (int id = tid; id < 24 * CC; id += 256) {
        const int fb = id / CC;
        const int j  = id - fb * CC;
        const uint4 v = *(const uint4*)(xp + j * FF + fb * 8);
        unsigned short* d = sXT + (fb * 8) * 40 + j;
        d[0 * 40] = (unsigned short)(v.x & 0xffffu);
        d[1 * 40] = (unsigned short)(v.x >> 16);
        d[2 * 40] = (unsigned short)(v.y & 0xffffu);
        d[3 * 40] = (unsigned short)(v.y >> 16);
        d[4 * 40] = (unsigned short)(v.z & 0xffffu);
        d[5 * 40] = (unsigned short)(v.z >> 16);
        d[6 * 40] = (unsigned short)(v.w & 0xffffu);
        d[7 * 40] = (unsigned short)(v.w >> 16);
    }
    __syncthreads();

    const int lane = tid & 63;
    const int wid  = tid >> 6;
    const int lr   = lane & 15;
    const int lk   = lane >> 4;
    const f32x4 vzero = {0.f, 0.f, 0.f, 0.f};

    {
        f32x4 acc[3][2];
        #pragma unroll
        for (int i = 0; i < 3; ++i)
            #pragma unroll
            for (int j = 0; j < 2; ++j) acc[i][j] = vzero;
        bf16x8 xa[3], ab[2];
        #pragma unroll
        for (int i = 0; i < 3; ++i)
            xa[i] = *(const bf16x8*)(sXT + ((3 * wid + i) * 16 + lr) * 40 + lk * 8);
        #pragma unroll
        for (int j = 0; j < 2; ++j)
            ab[j] = *(const bf16x8*)(sAm + (j * 16 + lr) * 40 + lk * 8);
        #pragma unroll
        for (int i = 0; i < 3; ++i)
            #pragma unroll
            for (int j = 0; j < 2; ++j)
                acc[i][j] = __builtin_amdgcn_mfma_f32_16x16x32_bf16(xa[i], ab[j], acc[i][j], 0, 0, 0);
        #pragma unroll
        for (int i = 0; i < 3; ++i) {
            const int fbase = (3 * wid + i) * 16 + lk * 4;
            #pragma unroll
            for (int j = 0; j < 2; ++j) {
                const int c = j * 16 + lr;
                ushort4 st;
                st.x = f2bf(acc[i][j][0]);
                st.y = f2bf(acc[i][j][1]);
                st.z = f2bf(acc[i][j][2]);
                st.w = f2bf(acc[i][j][3]);
                *(ushort4*)(sH1 + c * 200 + fbase) = st;
            }
        }
    }
    __syncthreads();

    {
        f32x4 acc[2][2];
        #pragma unroll
        for (int nt = 0; nt < 2; ++nt) {
            const float bv = bf2f(b0g[(2 * wid + nt) * 16 + lr]);
            f32x4 bvv = {bv, bv, bv, bv};
            acc[0][nt] = bvv;
            acc[1][nt] = bvv;
        }
        #pragma unroll
        for (int ks = 0; ks < 6; ++ks) {
            bf16x8 af[2], bfr[2];
            #pragma unroll
            for (int mt = 0; mt < 2; ++mt)
                af[mt] = *(const bf16x8*)(sH1 + (mt * 16 + lr) * 200 + ks * 32 + lk * 8);
            #pragma unroll
            for (int nt = 0; nt < 2; ++nt)
                bfr[nt] = *(const bf16x8*)(W0g + ((size_t)((2 * wid + nt) * 16 + lr)) * FF + ks * 32 + lk * 8);
            #pragma unroll
            for (int mt = 0; mt < 2; ++mt)
                #pragma unroll
                for (int nt = 0; nt < 2; ++nt)
                    acc[mt][nt] = __builtin_amdgcn_mfma_f32_16x16x32_bf16(af[mt], bfr[nt], acc[mt][nt], 0, 0, 0);
        }
        #pragma unroll
        for (int mt = 0; mt < 2; ++mt) {
            const int cbase = mt * 16 + lk * 4;
            #pragma unroll
            for (int nt = 0; nt < 2; ++nt) {
                const int hcol = (2 * wid + nt) * 16 + lr;
                ushort4 st;
                st.x = (cbase + 0 < CC) ? f2bf(fmaxf(acc[mt][nt][0], 0.f)) : (unsigned short)0;
                st.y = (cbase + 1 < CC) ? f2bf(fmaxf(acc[mt][nt][1], 0.f)) : (unsigned short)0;
                st.z = (cbase + 2 < CC) ? f2bf(fmaxf(acc[mt][nt][2], 0.f)) : (unsigned short)0;
                st.w = (cbase + 3 < CC) ? f2bf(fmaxf(acc[mt][nt][3], 0.f)) : (unsigned short)0;
                *(ushort4*)(sH2T + hcol * 40 + cbase) = st;
            }
        }
    }
    __syncthreads();

    {
        f32x4 acc[2][2];
        #pragma unroll
        for (int mt = 0; mt < 2; ++mt)
            #pragma unroll
            for (int ct = 0; ct < 2; ++ct) acc[mt][ct] = vzero;
        bf16x8 af[2], bb[2];
        #pragma unroll
        for (int mt = 0; mt < 2; ++mt)
            af[mt] = *(const bf16x8*)(sH2T + ((2 * wid + mt) * 16 + lr) * 40 + lk * 8);
        #pragma unroll
        for (int ct = 0; ct < 2; ++ct)
            bb[ct] = *(const bf16x8*)(sAm + (ct * 16 + lr) * 40 + lk * 8);
        #pragma unroll
        for (int mt = 0; mt < 2; ++mt)
            #pragma unroll
            for (int ct = 0; ct < 2; ++ct)
                acc[mt][ct] = __builtin_amdgcn_mfma_f32_16x16x32_bf16(af[mt], bb[ct], acc[mt][ct], 0, 0, 0);
        __syncthreads();   // sH1 fully consumed by P2 across waves before overwrite
        #pragma unroll
        for (int mt = 0; mt < 2; ++mt) {
            const int hbase = (2 * wid + mt) * 16 + lk * 4;
            #pragma unroll
            for (int ct = 0; ct < 2; ++ct) {
                const int c = ct * 16 + lr;
                ushort4 st;
                st.x = f2bf(acc[mt][ct][0]);
                st.y = f2bf(acc[mt][ct][1]);
                st.z = f2bf(acc[mt][ct][2]);
                st.w = f2bf(acc[mt][ct][3]);
                *(ushort4*)(sH3 + c * 136 + hbase) = st;
            }
        }
    }
    __syncthreads();

    {
        f32x4 acc[2][2];
        #pragma unroll
        for (int mt = 0; mt < 2; ++mt) {
            const ushort4 bu = *(const ushort4*)(b1g + (2 * wid + mt) * 16 + lk * 4);
            f32x4 bvv = {bf2f(bu.x), bf2f(bu.y), bf2f(bu.z), bf2f(bu.w)};
            acc[mt][0] = bvv;
            acc[mt][1] = bvv;
        }
        #pragma unroll
        for (int ks = 0; ks < 4; ++ks) {
            bf16x8 af[2], bfr[2];
            #pragma unroll
            for (int mt = 0; mt < 2; ++mt)
                af[mt] = *(const bf16x8*)(W1g + ((size_t)((2 * wid + mt) * 16 + lr)) * HH + ks * 32 + lk * 8);
            #pragma unroll
            for (int ct = 0; ct < 2; ++ct)
                bfr[ct] = *(const bf16x8*)(sH3 + (ct * 16 + lr) * 136 + ks * 32 + lk * 8);
            #pragma unroll
            for (int mt = 0; mt < 2; ++mt)
                #pragma unroll
                for (int ct = 0; ct < 2; ++ct)
                    acc[mt][ct] = __builtin_amdgcn_mfma_f32_16x16x32_bf16(af[mt], bfr[ct], acc[mt][ct], 0, 0, 0);
        }
        float s[2][4];
        #pragma unroll
        for (int mt = 0; mt < 2; ++mt)
            #pragma unroll
            for (int r = 0; r < 4; ++r) {
                float v = fmaxf(acc[mt][0][r], 0.f);
                if (lr < CC - 16) v += fmaxf(acc[mt][1][r], 0.f);
                s[mt][r] = v;
            }
        #pragma unroll
        for (int m = 1; m < 16; m <<= 1)
            #pragma unroll
            for (int mt = 0; mt < 2; ++mt)
                #pragma unroll
                for (int r = 0; r < 4; ++r)
                    s[mt][r] += __shfl_xor(s[mt][r], m);
        if (lr == 0) {
            const float inv = 1.0f / 22.0f;
            #pragma unroll
            for (int mt = 0; mt < 2; ++mt) {
                ushort4 st;
                st.x = f2bf(s[mt][0] * inv);
                st.y = f2bf(s[mt][1] * inv);
                st.z = f2bf(s[mt][2] * inv);
                st.w = f2bf(s[mt][3] * inv);
                *(ushort4*)(outg + (size_t)bt * HH + (2 * wid + mt) * 16 + lk * 4) = st;
            }
        }
    }
}

__global__ __launch_bounds__(256) void tgcn_kernel(
    const void* __restrict__ x, const void* __restrict__ A,
    const void* __restrict__ W0, const void* __restrict__ b0,
    const void* __restrict__ W1, const void* __restrict__ b1,
    void* __restrict__ out, const unsigned short* __restrict__ wsW,
    int use_split)
{
    __shared__ __align__(16) char smem[39104];   // 4 blocks/CU

    const int tid = threadIdx.x;
    const int bt  = blockIdx.x;
    const int isbf = inputs_are_bf16((const unsigned short*)A, tid);

    if (isbf) {
        run_block_bf16((const unsigned short*)x, (const unsigned short*)A,
                       (const unsigned short*)W0, (const unsigned short*)b0,
                       (const unsigned short*)W1, (const unsigned short*)b1,
                       (unsigned short*)out, bt, tid, smem);
    } else if (use_split) {
        run_block_split((const float*)x, (const float*)A,
                        (const float*)b0, (const float*)b1,
                        wsW, (float*)out, bt, tid, smem);
    } else {
        float* sA  = (float*)smem;                 // 1936B (later sRed)
        float* sX  = (float*)(smem + 1936);        // 16896B (later h2)
        float* sH1 = (float*)(smem + 18832);       // 16896B (later h3)
        run_block_f32((const float*)x, (const float*)A,
                      (const float*)W0, (const float*)b0,
                      (const float*)W1, (const float*)b1,
                      (float*)out, bt, tid, sA, sX, sH1);
    }
}

extern "C" void kernel_launch(void* const* d_in, const int* in_sizes, int n_in,
                              void* d_out, int out_size, void* d_ws, size_t ws_size,
                              hipStream_t stream) {
    unsigned short* wsW = (unsigned short*)d_ws;
    const int use_split = (ws_size >= (size_t)(81920 * 2)) ? 1 : 0;

    if (use_split)
        convert_weights<<<160, 256, 0, stream>>>(
            (const float*)d_in[2], (const float*)d_in[4],
            (const unsigned short*)d_in[1], wsW);
    tgcn_kernel<<<NBT, 256, 0, stream>>>(
        d_in[0], d_in[1], d_in[2], d_in[3], d_in[4], d_in[5], d_out,
        wsW, use_split);
}